// Round 10
// baseline (224.687 us; speedup 1.0000x reference)
//
#include <hip/hip_runtime.h>
#include <cstddef>

#define NT    32768
#define CCH   128
#define BB    64
#define NNODE 512
#define NHEAD 4
#define DHEAD 32
#define EE    524288
#define EPS   1e-5f
#define MAXDEG 96
#define CURPAD 16      // one cursor counter per 64B cache line
#define SSLOT  8       // stats atomic spreading slots
#define EGRP  2048     // edges per partition group (E / 256 groups)

typedef unsigned short u16;
typedef unsigned int   u32;
typedef __attribute__((ext_vector_type(8))) short short8;
typedef __attribute__((ext_vector_type(4))) short short4v;
typedef __attribute__((ext_vector_type(4))) float f32x4;

__device__ __forceinline__ float b2f(u32 w) { return __uint_as_float(w << 16); }
__device__ __forceinline__ u16 f2b(float f) {
    u32 u = __float_as_uint(f);
    u += 0x7FFF + ((u >> 16) & 1);   // RNE
    return (u16)(u >> 16);
}
// packed f32x2 -> bf16x2 (RNE), single instruction; no builtin on gfx950 (guide T12)
__device__ __forceinline__ u32 cvtpk(float lo, float hi) {
    u32 r;
    asm("v_cvt_pk_bf16_f32 %0, %1, %2" : "=v"(r) : "v"(lo), "v"(hi));
    return r;
}
#if __has_builtin(__builtin_amdgcn_exp2f)
#define EXP2(x) __builtin_amdgcn_exp2f(x)
#else
#define EXP2(x) exp2f(x)
#endif
// softmax scale (1/sqrt(32)) * log2(e), folded into Wq/bq at conversion time
#define SCLOG2E (0.1767766952966369f * 1.4426950408889634f)

// ---------------- prep: bf16 conversion (x + 5 weights); Wq/bq prescaled by SCLOG2E ----------------
__global__ __launch_bounds__(256) void prep_conv(const float* __restrict__ x,
                                                 const float* __restrict__ Wc,
                                                 const float* __restrict__ Wqkv,
                                                 const float* __restrict__ Wo,
                                                 const float* __restrict__ Wm1,
                                                 const float* __restrict__ Wm2,
                                                 u16* __restrict__ xb,
                                                 u16* __restrict__ Wcb,
                                                 u16* __restrict__ Wqkvb,
                                                 u16* __restrict__ Wob,
                                                 u16* __restrict__ Wm1b,
                                                 u16* __restrict__ Wm2b,
                                                 const float* __restrict__ bqkv,
                                                 float* __restrict__ bqs) {
    if (blockIdx.x == 2120) {
        // bias copy with q-part prescale
        int t = threadIdx.x;
        if (t < 384) {
            float v = bqkv[t];
            if (t < 128) v *= SCLOG2E;
            bqs[t] = v;
        }
        return;
    }
    int r = blockIdx.x * 256 + threadIdx.x;
    const float* src; u16* dst; float qs = 1.0f;
    if (r < 524288) { src = x; dst = xb; }
    else if ((r -= 524288) < 2048) { src = Wc; dst = Wcb; }
    else if ((r -= 2048) < 6144) { src = Wqkv; dst = Wqkvb; if (r < 2048) qs = SCLOG2E; }
    else if ((r -= 6144) < 2048) { src = Wo; dst = Wob; }
    else if ((r -= 2048) < 4096) { src = Wm1; dst = Wm1b; }
    else { r -= 4096; src = Wm2; dst = Wm2b; }
    size_t base = (size_t)r * 8;
    float4 a = *(const float4*)(src + base);
    float4 b = *(const float4*)(src + base + 4);
    uint4 u;
    u.x = cvtpk(a.x * qs, a.y * qs);
    u.y = cvtpk(a.z * qs, a.w * qs);
    u.z = cvtpk(b.x * qs, b.y * qs);
    u.w = cvtpk(b.z * qs, b.w * qs);
    *(uint4*)(dst + base) = u;
}

// ---------------- shared GEMM smem + body: 128x128 tile, dbuf + wide stores (27.6 KB) ----------------
struct GemmSmem {
    u16 As[128 * 32];      // 8 KB  (gather overlays int srcs[16][96] = 6 KB here)
    u16 Bs[128 * 32];      // 8 KB
    u16 Cs[4][16 * 72];    // 9 KB
    float csum[128];
    float csq[128];
};

// outb pre-offset to column 0 of this GEMM's output slice; ostride = its row stride.
// bias/residb indexed by LOCAL column (0..127); residb row stride = 128.
template <bool RELU, int RESID, bool STATS>
__device__ __forceinline__ void gemm_body(u16* __restrict__ As, u16* __restrict__ Bs,
                                          u16* __restrict__ Cs0, float* __restrict__ csum,
                                          float* __restrict__ csq,
                                          const u16* __restrict__ A,
                                          const u16* __restrict__ W,
                                          const float* __restrict__ bias,
                                          const u16* __restrict__ residb,
                                          u16* __restrict__ outb, int ostride,
                                          float* __restrict__ sum, float* __restrict__ sumsq,
                                          int slotbase, int m0, int K) {
    int tid = threadIdx.x;
    int lane = tid & 63, wave = tid >> 6;
    int wm = (wave & 1) * 64, wn = (wave >> 1) * 64;
    int l15 = lane & 15, l4 = lane >> 4;
    u16* Csw = Cs0 + wave * (16 * 72);

    if (STATS) {
        if (tid < 128) { csum[tid] = 0.f; csq[tid] = 0.f; }
    }

    f32x4 zero = {0.f, 0.f, 0.f, 0.f};
    f32x4 acc[4][4];
#pragma unroll
    for (int i = 0; i < 4; ++i)
#pragma unroll
        for (int j = 0; j < 4; ++j) acc[i][j] = zero;

    int srow = tid >> 2;
    int scol = (tid & 3) * 8;

    int kIter = K >> 5;
    uint4 a0 = *(const uint4*)(A + (size_t)(m0 + srow) * K + scol);
    uint4 a1 = *(const uint4*)(A + (size_t)(m0 + srow + 64) * K + scol);
    uint4 b0 = *(const uint4*)(W + (size_t)srow * K + scol);
    uint4 b1 = *(const uint4*)(W + (size_t)(srow + 64) * K + scol);
    for (int ki = 0; ki < kIter; ++ki) {
        if (ki) __syncthreads();
        *(uint4*)&As[srow * 32 + scol] = a0;
        *(uint4*)&As[(srow + 64) * 32 + scol] = a1;
        *(uint4*)&Bs[srow * 32 + scol] = b0;
        *(uint4*)&Bs[(srow + 64) * 32 + scol] = b1;
        if (ki + 1 < kIter) {
            int k0 = (ki + 1) * 32;
            a0 = *(const uint4*)(A + (size_t)(m0 + srow) * K + k0 + scol);
            a1 = *(const uint4*)(A + (size_t)(m0 + srow + 64) * K + k0 + scol);
            b0 = *(const uint4*)(W + (size_t)srow * K + k0 + scol);
            b1 = *(const uint4*)(W + (size_t)(srow + 64) * K + k0 + scol);
        }
        __syncthreads();
        short8 af[4], bf[4];
#pragma unroll
        for (int t = 0; t < 4; ++t) {
            af[t] = *(const short8*)&As[(wm + t * 16 + l15) * 32 + l4 * 8];
            bf[t] = *(const short8*)&Bs[(wn + t * 16 + l15) * 32 + l4 * 8];
        }
#pragma unroll
        for (int mt = 0; mt < 4; ++mt)
#pragma unroll
            for (int nt = 0; nt < 4; ++nt)
                acc[mt][nt] = __builtin_amdgcn_mfma_f32_16x16x32_bf16(af[mt], bf[nt], acc[mt][nt], 0, 0, 0);
    }

    float ps[4] = {0.f, 0.f, 0.f, 0.f};
    float pq[4] = {0.f, 0.f, 0.f, 0.f};
    int rl = lane >> 3;          // 0..7
    int cg = lane & 7;           // 0..7
#pragma unroll
    for (int mt = 0; mt < 4; ++mt) {
#pragma unroll
        for (int nt = 0; nt < 4; ++nt) {
            int lcol = wn + nt * 16 + l15;
            float bs = bias[lcol];
#pragma unroll
            for (int r = 0; r < 4; ++r) {
                int row = m0 + wm + mt * 16 + l4 * 4 + r;
                float v = acc[mt][nt][r] + bs;
                if (RESID == 2) v += b2f(residb[(size_t)row * 128 + lcol]);
                if (RELU) v = fmaxf(v, 0.0f);
                Csw[(l4 * 4 + r) * 72 + nt * 16 + l15] = f2b(v);
                if (STATS) { ps[nt] += v; pq[nt] += v * v; }
            }
        }
        // wide readback + coalesced store (wave-private, DS in-order: no barrier)
#pragma unroll
        for (int p = 0; p < 2; ++p) {
            int lrow = p * 8 + rl;
            uint4 wv = *(const uint4*)&Csw[lrow * 72 + cg * 8];
            int grow = m0 + wm + mt * 16 + lrow;
            *(uint4*)(outb + (size_t)grow * ostride + wn + cg * 8) = wv;
        }
    }
    if (STATS) {
#pragma unroll
        for (int nt = 0; nt < 4; ++nt) {
            atomicAdd(&csum[wn + nt * 16 + l15], ps[nt]);
            atomicAdd(&csq[wn + nt * 16 + l15], pq[nt]);
        }
        __syncthreads();
        if (tid < 128) {
            atomicAdd(sum + slotbase + tid, csum[tid]);
            atomicAdd(sumsq + slotbase + tid, csq[tid]);
        }
    }
}

// ---------------- fused: XCD-partitioned bucket fill (8/group) + QKV GEMM (3/group) ----------------
// 256 groups x 11 blocks = 2816. Fill (atomic/memory-bound) and QKV (MFMA-bound) interleave per-CU.
// Fill keeps XCD-residue alignment: for fixed group g, slots s=0..7 give bid&7 = (3g+s)&7 = all 8.
__global__ __launch_bounds__(256) void qkv_fill(const u16* __restrict__ xb,
                                                const u16* __restrict__ Wqkvb,
                                                const float* __restrict__ bqs,
                                                u16* __restrict__ qkvb,
                                                const int* __restrict__ ei,
                                                int* __restrict__ cursor,
                                                int* __restrict__ bucket) {
    __shared__ GemmSmem sm;
    int bid = blockIdx.x;
    int g = bid / 11, s = bid % 11;
    if (s < 8) {
        int k = bid & 7;               // this block's XCD residue == its dst partition
        int base_e = g * EGRP;
        for (int j = threadIdx.x; j < EGRP; j += 256) {
            int dst = ei[EE + base_e + j];
            if ((dst & 7) == k) {
                int src = ei[base_e + j];
                int pos = atomicAdd(cursor + dst * CURPAD, 1);
                if (pos < MAXDEG) bucket[dst * MAXDEG + pos] = src;
            }
        }
        return;
    }
    int q = g * 3 + (s - 8);           // 0..767
    int y = q % 3;
    int m0 = (q / 3) * 128;
    gemm_body<false, 0, false>(sm.As, sm.Bs, &sm.Cs[0][0], sm.csum, sm.csq,
                               xb, Wqkvb + (size_t)y * 16384, bqs + y * 128, nullptr,
                               qkvb + y * 128, 384, nullptr, nullptr, 0, m0, 128);
}

// ---------------- fused: attention (bid<256) + gather-aggregate+Wc GEMM (bid>=256) ----------------
struct K3Smem {
    union {
        struct { u16 Ks[512 * 40]; u16 Vt[32 * 520]; } a;   // 72.5 KB attention
        GemmSmem g;                                          // 27.6 KB gather+Wc
    };
};

__global__ __launch_bounds__(256) void attn_gwc(const u16* __restrict__ qkv,
                                                u16* __restrict__ o,
                                                const int* __restrict__ bucket,
                                                const int* __restrict__ cursor,
                                                const u16* __restrict__ Wcb,
                                                const float* __restrict__ bc,
                                                const u16* __restrict__ xb,
                                                u16* __restrict__ aggb,
                                                u16* __restrict__ hlocb,
                                                float* __restrict__ sum1,
                                                float* __restrict__ sq1) {
    __shared__ __align__(16) K3Smem sm;
    int bid = blockIdx.x;
    int tid = threadIdx.x;

    if (bid < 256) {
        // ---- attention branch: 4 waves, each covers 128 q-rows (8 q-tiles).
        //      q is prescaled by scale*log2e -> softmax is a bare exp2; P packed via cvt_pk.
        u16* Ks = sm.a.Ks;
        u16* Vt = sm.a.Vt;
        int b = bid >> 2, h = bid & 3;
        int lane = tid & 63, wave = tid >> 6;
        int quad = lane >> 4, l15 = lane & 15;

        const u16* kvbase = qkv + (size_t)b * 512 * 384 + 128 + h * 32;
        for (int idx = tid; idx < 2048; idx += 256) {
            int row = idx >> 2, c = idx & 3;
            *(uint4*)&Ks[row * 40 + c * 8] = *(const uint4*)(kvbase + (size_t)row * 384 + c * 8);
        }
        for (int idx = tid; idx < 2048; idx += 256) {
            int row = idx >> 2, c = idx & 3;
            uint4 u = *(const uint4*)(kvbase + 128 + (size_t)row * 384 + c * 8);
            u16 e[8];
            *(uint4*)e = u;
#pragma unroll
            for (int i = 0; i < 8; ++i) Vt[(c * 8 + i) * 520 + row] = e[i];
        }
        __syncthreads();

        f32x4 zero = {0.f, 0.f, 0.f, 0.f};
        for (int qt = 0; qt < 8; ++qt) {
            int qbase = wave * 128 + qt * 16;
            short8 qf = *(const short8*)(qkv + (size_t)(b * 512 + qbase + l15) * 384 + h * 32 + quad * 8);
            float lq = 0.f;
            f32x4 oa[2] = {zero, zero};

            for (int kv0 = 0; kv0 < 512; kv0 += 64) {
                f32x4 s[4];
#pragma unroll
                for (int t = 0; t < 4; ++t) {
                    short8 kb = *(const short8*)&Ks[(kv0 + t * 16 + l15) * 40 + quad * 8];
                    s[t] = __builtin_amdgcn_mfma_f32_16x16x32_bf16(kb, qf, zero, 0, 0, 0);
                }
                // exp2 (scale folded into q) + packed bf16 convert; two 16-kv tiles per A-operand
                u32 ppw[2][4];
#pragma unroll
                for (int t = 0; t < 4; ++t) {
                    float p0 = EXP2(s[t][0]);
                    float p1 = EXP2(s[t][1]);
                    float p2 = EXP2(s[t][2]);
                    float p3 = EXP2(s[t][3]);
                    lq += (p0 + p1) + (p2 + p3);
                    ppw[t >> 1][(t & 1) * 2 + 0] = cvtpk(p0, p1);
                    ppw[t >> 1][(t & 1) * 2 + 1] = cvtpk(p2, p3);
                }
                short8 pps[2];
                pps[0] = *(const short8*)&ppw[0][0];
                pps[1] = *(const short8*)&ppw[1][0];
#pragma unroll
                for (int tp = 0; tp < 2; ++tp) {
                    int tb = kv0 + tp * 32;
#pragma unroll
                    for (int n = 0; n < 2; ++n) {
                        const u16* vrow = &Vt[(n * 16 + l15) * 520 + tb + quad * 4];
                        short4v va = *(const short4v*)vrow;          // kv tile 2tp
                        short4v vb2 = *(const short4v*)(vrow + 16);  // kv tile 2tp+1
                        short8 vv = {va.x, va.y, va.z, va.w, vb2.x, vb2.y, vb2.z, vb2.w};
                        oa[n] = __builtin_amdgcn_mfma_f32_16x16x32_bf16(pps[tp], vv, oa[n], 0, 0, 0);
                    }
                }
            }
            lq += __shfl_xor(lq, 16);
            lq += __shfl_xor(lq, 32);
            u16* op = o + (size_t)(b * 512 + qbase) * 128 + h * 32;
#pragma unroll
            for (int r = 0; r < 4; ++r) {
                float Lr = __shfl(lq, quad * 4 + r);
                float inv = 1.0f / Lr;
#pragma unroll
                for (int n = 0; n < 2; ++n)
                    op[(quad * 4 + r) * 128 + n * 16 + l15] = f2b(oa[n][r] * inv);
            }
        }
        return;
    }

    // ---- gather+Wc branch ----
    int m0 = (bid - 256) * 128;

    // phase 1: gather-aggregate this block's 128 nodes -> aggb (global; same-XCD L2 hit)
    {
        int (*srcs)[MAXDEG] = reinterpret_cast<int (*)[MAXDEG]>(sm.g.As);  // 6 KB overlay in As
        int ln = tid >> 4;     // node-in-pass 0..15
        int c8 = tid & 15;     // channel block of 8
        const u16* xp = xb + c8 * 8;
        for (int pass = 0; pass < 8; ++pass) {
            int n = pass * 16 + ln;          // local row 0..127
            int gn = m0 + n;
            int d = min(cursor[gn * CURPAD], MAXDEG);
            for (int j = c8; j < d; j += 16) srcs[ln][j] = bucket[gn * MAXDEG + j];
            __syncthreads();
            float s[8] = {0.f, 0.f, 0.f, 0.f, 0.f, 0.f, 0.f, 0.f};
            for (int base = 0; base < d; base += 8) {
                uint4 w[8];
#pragma unroll
                for (int u = 0; u < 8; ++u) {
                    int jj = base + u;
                    int idx = srcs[ln][jj < d ? jj : 0];
                    w[u] = *(const uint4*)(xp + (size_t)idx * CCH);
                }
#pragma unroll
                for (int u = 0; u < 8; ++u) {
                    if (base + u >= d) { w[u].x = 0; w[u].y = 0; w[u].z = 0; w[u].w = 0; }
                    s[0] += b2f(w[u].x & 0xffffu);
                    s[1] += b2f(w[u].x >> 16);
                    s[2] += b2f(w[u].y & 0xffffu);
                    s[3] += b2f(w[u].y >> 16);
                    s[4] += b2f(w[u].z & 0xffffu);
                    s[5] += b2f(w[u].z >> 16);
                    s[6] += b2f(w[u].w & 0xffffu);
                    s[7] += b2f(w[u].w >> 16);
                }
            }
            float inv = 1.0f / fmaxf((float)d, 1.0f);
            uint4 out;
            out.x = cvtpk(s[0] * inv, s[1] * inv);
            out.y = cvtpk(s[2] * inv, s[3] * inv);
            out.z = cvtpk(s[4] * inv, s[5] * inv);
            out.w = cvtpk(s[6] * inv, s[7] * inv);
            *(uint4*)(aggb + (size_t)gn * CCH + c8 * 8) = out;
            __syncthreads();   // srcs reused next pass
        }
    }
    __syncthreads();

    // phase 2: standard Wc GEMM, A = aggb (just written by this block -> L2-hot)
    gemm_body<false, 2, true>(sm.g.As, sm.g.Bs, &sm.g.Cs[0][0], sm.g.csum, sm.g.csq,
                              aggb, Wcb, bc, xb, hlocb, 128, sum1, sq1,
                              ((bid - 256) & (SSLOT - 1)) << 7, m0, 128);
}

// ---------------- Wo GEMM wrapper ----------------
__global__ __launch_bounds__(256) void gemm_wo(const u16* __restrict__ ob,
                                               const u16* __restrict__ Wob,
                                               const float* __restrict__ bo,
                                               const u16* __restrict__ xb,
                                               u16* __restrict__ t2b,
                                               float* __restrict__ sum2, float* __restrict__ sq2) {
    __shared__ GemmSmem sm;
    gemm_body<false, 2, true>(sm.As, sm.Bs, &sm.Cs[0][0], sm.csum, sm.csq,
                              ob, Wob, bo, xb, t2b, 128, sum2, sq2,
                              (blockIdx.x & (SSLOT - 1)) << 7, blockIdx.x * 128, 128);
}

// ---------------- MLP2 GEMM wrapper ----------------
__global__ __launch_bounds__(256) void gemm_mlp2(const u16* __restrict__ hidb,
                                                 const u16* __restrict__ Wm2b,
                                                 const float* __restrict__ bm2,
                                                 const u16* __restrict__ shb,
                                                 u16* __restrict__ out2b,
                                                 float* __restrict__ sum3, float* __restrict__ sq3) {
    __shared__ GemmSmem sm;
    gemm_body<false, 2, true>(sm.As, sm.Bs, &sm.Cs[0][0], sm.csum, sm.csq,
                              hidb, Wm2b, bm2, shb, out2b, 128, sum3, sq3,
                              (blockIdx.x & (SSLOT - 1)) << 7, blockIdx.x * 128, 256);
}

// ---------------- MLP1 GEMM with comb fused into A-staging; dbuf + wide stores ----------------
__global__ __launch_bounds__(256) void gemm_m1c(const u16* __restrict__ hlocb,
                                                const u16* __restrict__ t2b,
                                                const float* __restrict__ sum1,
                                                const float* __restrict__ sq1,
                                                const float* __restrict__ g1,
                                                const float* __restrict__ bt1,
                                                const float* __restrict__ sum2,
                                                const float* __restrict__ sq2,
                                                const float* __restrict__ g2,
                                                const float* __restrict__ bt2,
                                                u16* __restrict__ shb,
                                                const u16* __restrict__ Wm1b,
                                                const float* __restrict__ bm1,
                                                u16* __restrict__ hidb) {
    __shared__ u16 As[128 * 32];
    __shared__ u16 Bs[128 * 32];
    __shared__ u16 Cs[4][16 * 72];
    __shared__ float AF1[128], BF1[128], AF2[128], BF2[128];
    int tid = threadIdx.x;
    {
        int c = tid & 127;
        const float* sm = (tid < 128) ? sum1 : sum2;
        const float* sq = (tid < 128) ? sq1 : sq2;
        const float* g  = (tid < 128) ? g1 : g2;
        const float* bt = (tid < 128) ? bt1 : bt2;
        float s = 0.f, q = 0.f;
#pragma unroll
        for (int sl = 0; sl < SSLOT; ++sl) { s += sm[sl * 128 + c]; q += sq[sl * 128 + c]; }
        float m = s * (1.0f / NT);
        float v = q * (1.0f / NT) - m * m;
        float a = g[c] * rsqrtf(v + EPS);
        if (tid < 128) { AF1[c] = a; BF1[c] = bt[c] - m * a; }
        else           { AF2[c] = a; BF2[c] = bt[c] - m * a; }
    }
    int m0 = blockIdx.x * 128, n0 = blockIdx.y * 128;
    int lane = tid & 63, wave = tid >> 6;
    int wm = (wave & 1) * 64, wn = (wave >> 1) * 64;
    int l15 = lane & 15, l4 = lane >> 4;

    f32x4 zero = {0.f, 0.f, 0.f, 0.f};
    f32x4 acc[4][4];
#pragma unroll
    for (int i = 0; i < 4; ++i)
#pragma unroll
        for (int j = 0; j < 4; ++j) acc[i][j] = zero;

    int srow = tid >> 2;
    int scol = (tid & 3) * 8;
    bool wr = (blockIdx.y == 0);

    uint4 h0 = *(const uint4*)(hlocb + (size_t)(m0 + srow) * 128 + scol);
    uint4 h1 = *(const uint4*)(hlocb + (size_t)(m0 + srow + 64) * 128 + scol);
    uint4 t0 = *(const uint4*)(t2b + (size_t)(m0 + srow) * 128 + scol);
    uint4 t1 = *(const uint4*)(t2b + (size_t)(m0 + srow + 64) * 128 + scol);
    uint4 b0 = *(const uint4*)(Wm1b + (size_t)(n0 + srow) * 128 + scol);
    uint4 b1 = *(const uint4*)(Wm1b + (size_t)(n0 + srow + 64) * 128 + scol);
    // barrier for AF/BF shared arrays before first use
    __syncthreads();
    for (int ki = 0; ki < 4; ++ki) {
        int k0 = ki * 32;
        if (ki) __syncthreads();
        uint4 c0, c1;
        {
            const u32 hw[4] = {h0.x, h0.y, h0.z, h0.w};
            const u32 tw[4] = {t0.x, t0.y, t0.z, t0.w};
            u32 ow[4];
#pragma unroll
            for (int p = 0; p < 4; ++p) {
                int cc = k0 + scol + p * 2;
                float v0 = AF1[cc] * b2f(hw[p] & 0xffffu) + BF1[cc] + AF2[cc] * b2f(tw[p] & 0xffffu) + BF2[cc];
                float v1 = AF1[cc + 1] * b2f(hw[p] >> 16) + BF1[cc + 1] + AF2[cc + 1] * b2f(tw[p] >> 16) + BF2[cc + 1];
                ow[p] = cvtpk(v0, v1);
            }
            c0.x = ow[0]; c0.y = ow[1]; c0.z = ow[2]; c0.w = ow[3];
        }
        {
            const u32 hw[4] = {h1.x, h1.y, h1.z, h1.w};
            const u32 tw[4] = {t1.x, t1.y, t1.z, t1.w};
            u32 ow[4];
#pragma unroll
            for (int p = 0; p < 4; ++p) {
                int cc = k0 + scol + p * 2;
                float v0 = AF1[cc] * b2f(hw[p] & 0xffffu) + BF1[cc] + AF2[cc] * b2f(tw[p] & 0xffffu) + BF2[cc];
                float v1 = AF1[cc + 1] * b2f(hw[p] >> 16) + BF1[cc + 1] + AF2[cc + 1] * b2f(tw[p] >> 16) + BF2[cc + 1];
                ow[p] = cvtpk(v0, v1);
            }
            c1.x = ow[0]; c1.y = ow[1]; c1.z = ow[2]; c1.w = ow[3];
        }
        *(uint4*)&As[srow * 32 + scol] = c0;
        *(uint4*)&As[(srow + 64) * 32 + scol] = c1;
        *(uint4*)&Bs[srow * 32 + scol] = b0;
        *(uint4*)&Bs[(srow + 64) * 32 + scol] = b1;
        if (wr) {
            *(uint4*)(shb + (size_t)(m0 + srow) * 128 + k0 + scol) = c0;
            *(uint4*)(shb + (size_t)(m0 + srow + 64) * 128 + k0 + scol) = c1;
        }
        if (ki < 3) {
            int kn = k0 + 32;
            h0 = *(const uint4*)(hlocb + (size_t)(m0 + srow) * 128 + kn + scol);
            h1 = *(const uint4*)(hlocb + (size_t)(m0 + srow + 64) * 128 + kn + scol);
            t0 = *(const uint4*)(t2b + (size_t)(m0 + srow) * 128 + kn + scol);
            t1 = *(const uint4*)(t2b + (size_t)(m0 + srow + 64) * 128 + kn + scol);
            b0 = *(const uint4*)(Wm1b + (size_t)(n0 + srow) * 128 + kn + scol);
            b1 = *(const uint4*)(Wm1b + (size_t)(n0 + srow + 64) * 128 + kn + scol);
        }
        __syncthreads();
        short8 af[4], bf[4];
#pragma unroll
        for (int t = 0; t < 4; ++t) {
            af[t] = *(const short8*)&As[(wm + t * 16 + l15) * 32 + l4 * 8];
            bf[t] = *(const short8*)&Bs[(wn + t * 16 + l15) * 32 + l4 * 8];
        }
#pragma unroll
        for (int mt = 0; mt < 4; ++mt)
#pragma unroll
            for (int nt = 0; nt < 4; ++nt)
                acc[mt][nt] = __builtin_amdgcn_mfma_f32_16x16x32_bf16(af[mt], bf[nt], acc[mt][nt], 0, 0, 0);
    }

    int rl = lane >> 3;
    int cg = lane & 7;
#pragma unroll
    for (int mt = 0; mt < 4; ++mt) {
#pragma unroll
        for (int nt = 0; nt < 4; ++nt) {
            int col = n0 + wn + nt * 16 + l15;
            float bs = bm1[col];
#pragma unroll
            for (int r = 0; r < 4; ++r) {
                float v = fmaxf(acc[mt][nt][r] + bs, 0.0f);
                Cs[wave][(l4 * 4 + r) * 72 + nt * 16 + l15] = f2b(v);
            }
        }
#pragma unroll
        for (int p = 0; p < 2; ++p) {
            int lrow = p * 8 + rl;
            uint4 wv = *(const uint4*)&Cs[wave][lrow * 72 + cg * 8];
            int grow = m0 + wm + mt * 16 + lrow;
            *(uint4*)(hidb + (size_t)grow * 256 + n0 + wn + cg * 8) = wv;
        }
    }
}

// ---------------- final = bn3(out2), affine in-block, bf16 -> fp32 ----------------
__global__ __launch_bounds__(256) void final_bn(const u16* __restrict__ X,
                                                const float* __restrict__ sum3,
                                                const float* __restrict__ sq3,
                                                const float* __restrict__ g3,
                                                const float* __restrict__ bt3,
                                                float* __restrict__ outp) {
    __shared__ float A3[128], B3[128];
    int t = threadIdx.x;
    if (t < 128) {
        float s = 0.f, q = 0.f;
#pragma unroll
        for (int sl = 0; sl < SSLOT; ++sl) { s += sum3[sl * 128 + t]; q += sq3[sl * 128 + t]; }
        float m = s * (1.0f / NT);
        float v = q * (1.0f / NT) - m * m;
        float a = g3[t] * rsqrtf(v + EPS);
        A3[t] = a;
        B3[t] = bt3[t] - m * a;
    }
    __syncthreads();
    int i8 = blockIdx.x * 256 + t;
    size_t i = (size_t)i8 * 8;
    int c = (int)(i & (CCH - 1));
    uint4 u = *(const uint4*)(X + i);
    float x[8];
    x[0] = b2f(u.x & 0xffffu); x[1] = b2f(u.x >> 16);
    x[2] = b2f(u.y & 0xffffu); x[3] = b2f(u.y >> 16);
    x[4] = b2f(u.z & 0xffffu); x[5] = b2f(u.z >> 16);
    x[6] = b2f(u.w & 0xffffu); x[7] = b2f(u.w >> 16);
    float4 o0, o1;
    o0.x = A3[c + 0] * x[0] + B3[c + 0];
    o0.y = A3[c + 1] * x[1] + B3[c + 1];
    o0.z = A3[c + 2] * x[2] + B3[c + 2];
    o0.w = A3[c + 3] * x[3] + B3[c + 3];
    o1.x = A3[c + 4] * x[4] + B3[c + 4];
    o1.y = A3[c + 5] * x[5] + B3[c + 5];
    o1.z = A3[c + 6] * x[6] + B3[c + 6];
    o1.w = A3[c + 7] * x[7] + B3[c + 7];
    *(float4*)(outp + i) = o0;
    *(float4*)(outp + i + 4) = o1;
}

extern "C" void kernel_launch(void* const* d_in, const int* in_sizes, int n_in,
                              void* d_out, int out_size, void* d_ws, size_t ws_size,
                              hipStream_t stream) {
    const float* x    = (const float*)d_in[0];
    const int*   ei   = (const int*)d_in[1];
    const float* Wc   = (const float*)d_in[2];
    const float* bc   = (const float*)d_in[3];
    const float* Wqkv = (const float*)d_in[4];
    const float* bqkv = (const float*)d_in[5];
    const float* Wo   = (const float*)d_in[6];
    const float* bo   = (const float*)d_in[7];
    const float* gn1  = (const float*)d_in[8];
    const float* bn1b = (const float*)d_in[9];
    const float* gn2  = (const float*)d_in[10];
    const float* bn2b = (const float*)d_in[11];
    const float* gn3  = (const float*)d_in[12];
    const float* bn3b = (const float*)d_in[13];
    const float* Wm1  = (const float*)d_in[14];
    const float* bm1  = (const float*)d_in[15];
    const float* Wm2  = (const float*)d_in[16];
    const float* bm2  = (const float*)d_in[17];
    float* outp = (float*)d_out;

    char* w = (char*)d_ws;
    const size_t MB = 1024 * 1024;
    u16* xb    = (u16*)(w);                     //  8 MB
    u16* hlocb = (u16*)(w + 8 * MB);            //  8 MB
    u16* t2b   = (u16*)(w + 16 * MB);           //  8 MB  h_attn
    u16* out2b = (u16*)(w + 24 * MB);           //  8 MB
    u16* qkvb  = (u16*)(w + 32 * MB);           // 24 MB
    u16* hidb  = (u16*)(w + 56 * MB);           // 16 MB  [NT,256]
    u16* shb   = (u16*)(w + 72 * MB);           //  8 MB  aggb -> comb
    int* bucket = (int*)(w + 80 * MB);          // 12 MB
    int* cursor = (int*)(w + 92 * MB);          //  2 MB (padded: 1 counter / 64B line)
    float* stats = (float*)(w + 94 * MB);       //  stats (6x1024 floats) + bqs (384 floats)
    u16* Wcb   = (u16*)(w + 95 * MB);
    u16* Wqkvb = Wcb + 16384;
    u16* Wob   = Wqkvb + 49152;
    u16* Wm1b  = Wob + 16384;
    u16* Wm2b  = Wm1b + 32768;
    u16* ob    = (u16*)(w + 96 * MB);           //  8 MB  attention output (own buffer)
    float* sum1 = stats;                  float* sq1 = stats + 1024;
    float* sum2 = stats + 2048;           float* sq2 = stats + 3072;
    float* sum3 = stats + 4096;           float* sq3 = stats + 5120;
    float* bqs  = stats + 6144;           // prescaled qkv bias (384 floats)

    // cursor (2 MB) and stats (24 KB) are contiguous: one memset
    hipMemsetAsync(cursor, 0, 2 * MB + 6 * 1024 * 4, stream);

    prep_conv<<<2121, 256, 0, stream>>>(x, Wc, Wqkv, Wo, Wm1, Wm2,
                                        xb, Wcb, Wqkvb, Wob, Wm1b, Wm2b, bqkv, bqs);

    // fused: XCD-partitioned bucket fill co-scheduled with QKV GEMMs (256 groups x {8 fill + 3 qkv})
    qkv_fill<<<2816, 256, 0, stream>>>(xb, Wqkvb, bqs, qkvb, ei, cursor, bucket);

    // fused: attention (256 blocks) co-scheduled with gather+Wc (256 blocks)
    attn_gwc<<<512, 256, 0, stream>>>(qkvb, ob, bucket, cursor, Wcb, bc, xb,
                                      shb /*aggb*/, hlocb, sum1, sq1);

    gemm_wo<<<NT / 128, 256, 0, stream>>>(ob, Wob, bo, xb, t2b, sum2, sq2);

    {
        dim3 g(NT / 128, 2);
        gemm_m1c<<<g, 256, 0, stream>>>(hlocb, t2b, sum1, sq1, gn1, bn1b,
                                        sum2, sq2, gn2, bn2b, shb, Wm1b, bm1, hidb);
    }

    gemm_mlp2<<<NT / 128, 256, 0, stream>>>(hidb, Wm2b, bm2, shb, out2b, sum3, sq3);

    final_bn<<<NT * CCH / 8 / 256, 256, 0, stream>>>(out2b, sum3, sq3, gn3, bn3b, outp);
}

// Round 11
// 220.093 us; speedup vs baseline: 1.0209x; 1.0209x over previous
//
#include <hip/hip_runtime.h>
#include <cstddef>

#define NT    32768
#define CCH   128
#define BB    64
#define NNODE 512
#define NHEAD 4
#define DHEAD 32
#define EE    524288
#define EPS   1e-5f
#define MAXDEG 96
#define CURPAD 16      // one cursor counter per 64B cache line
#define SSLOT  8       // stats atomic spreading slots
#define EGRP  2048     // edges per partition group (E / 256 groups)
#define FILL0 2128     // first fill block (8-aligned so (bid-FILL0)&7 == bid&7)

typedef unsigned short u16;
typedef unsigned int   u32;
typedef __attribute__((ext_vector_type(8))) short short8;
typedef __attribute__((ext_vector_type(4))) short short4v;
typedef __attribute__((ext_vector_type(4))) float f32x4;

__device__ __forceinline__ float b2f(u32 w) { return __uint_as_float(w << 16); }
__device__ __forceinline__ u16 f2b(float f) {
    u32 u = __float_as_uint(f);
    u += 0x7FFF + ((u >> 16) & 1);   // RNE
    return (u16)(u >> 16);
}
// packed f32x2 -> bf16x2 (RNE), single instruction; no builtin on gfx950 (guide T12)
__device__ __forceinline__ u32 cvtpk(float lo, float hi) {
    u32 r;
    asm("v_cvt_pk_bf16_f32 %0, %1, %2" : "=v"(r) : "v"(lo), "v"(hi));
    return r;
}
#if __has_builtin(__builtin_amdgcn_exp2f)
#define EXP2(x) __builtin_amdgcn_exp2f(x)
#else
#define EXP2(x) exp2f(x)
#endif
// softmax scale (1/sqrt(32)) * log2(e), folded into Wq/bq at conversion time
#define SCLOG2E (0.1767766952966369f * 1.4426950408889634f)

// ---------------- prep: bf16 conversion (Wq/bq prescaled) + XCD-partitioned bucket fill ------------
// NO __shared__ in this kernel: fill blocks need max occupancy (8 blocks/CU) for atomic/scatter TLP.
// (Round-10 lesson: putting fill in a 26.6KB-LDS kernel cut it to 5 blocks/CU -> 54us regression.)
__global__ __launch_bounds__(256) void prep_kernel(const float* __restrict__ x,
                                                   const float* __restrict__ Wc,
                                                   const float* __restrict__ Wqkv,
                                                   const float* __restrict__ Wo,
                                                   const float* __restrict__ Wm1,
                                                   const float* __restrict__ Wm2,
                                                   u16* __restrict__ xb,
                                                   u16* __restrict__ Wcb,
                                                   u16* __restrict__ Wqkvb,
                                                   u16* __restrict__ Wob,
                                                   u16* __restrict__ Wm1b,
                                                   u16* __restrict__ Wm2b,
                                                   const float* __restrict__ bqkv,
                                                   float* __restrict__ bqs,
                                                   const int* __restrict__ ei,
                                                   int* __restrict__ cursor,
                                                   int* __restrict__ bucket) {
    int bid = blockIdx.x;
    if (bid >= FILL0) {
        // 2048 fill blocks = 256 groups x 8 XCD-slots; (bid-FILL0)&7 == bid&7 (XCD residue).
        int b2 = bid - FILL0;
        int k = b2 & 7;
        int g = b2 >> 3;
        int base_e = g * EGRP;
        for (int j = threadIdx.x; j < EGRP; j += 256) {
            int dst = ei[EE + base_e + j];
            if ((dst & 7) == k) {
                int src = ei[base_e + j];
                int pos = atomicAdd(cursor + dst * CURPAD, 1);
                if (pos < MAXDEG) bucket[dst * MAXDEG + pos] = src;
            }
        }
        return;
    }
    if (bid == 2120) {
        int t = threadIdx.x;
        if (t < 384) {
            float v = bqkv[t];
            if (t < 128) v *= SCLOG2E;
            bqs[t] = v;
        }
        return;
    }
    if (bid > 2120) return;   // 2121..2127 idle (alignment padding)
    int r = bid * 256 + threadIdx.x;
    const float* src; u16* dst; float qs = 1.0f;
    if (r < 524288) { src = x; dst = xb; }
    else if ((r -= 524288) < 2048) { src = Wc; dst = Wcb; }
    else if ((r -= 2048) < 6144) { src = Wqkv; dst = Wqkvb; if (r < 2048) qs = SCLOG2E; }
    else if ((r -= 6144) < 2048) { src = Wo; dst = Wob; }
    else if ((r -= 2048) < 4096) { src = Wm1; dst = Wm1b; }
    else { r -= 4096; src = Wm2; dst = Wm2b; }
    size_t base = (size_t)r * 8;
    float4 a = *(const float4*)(src + base);
    float4 b = *(const float4*)(src + base + 4);
    uint4 u;
    u.x = cvtpk(a.x * qs, a.y * qs);
    u.y = cvtpk(a.z * qs, a.w * qs);
    u.z = cvtpk(b.x * qs, b.y * qs);
    u.w = cvtpk(b.z * qs, b.w * qs);
    *(uint4*)(dst + base) = u;
}

// ---------------- shared GEMM smem + body: 128x128 tile, dbuf + wide stores (27.6 KB) ----------------
struct GemmSmem {
    u16 As[128 * 32];      // 8 KB  (gather overlays int srcs[16][96] = 6 KB here)
    u16 Bs[128 * 32];      // 8 KB
    u16 Cs[4][16 * 72];    // 9 KB
    float csum[128];
    float csq[128];
};

// outb pre-offset to column 0 of this GEMM's output slice; ostride = its row stride.
// bias/residb indexed by LOCAL column (0..127); residb row stride = 128.
template <bool RELU, int RESID, bool STATS>
__device__ __forceinline__ void gemm_body(u16* __restrict__ As, u16* __restrict__ Bs,
                                          u16* __restrict__ Cs0, float* __restrict__ csum,
                                          float* __restrict__ csq,
                                          const u16* __restrict__ A,
                                          const u16* __restrict__ W,
                                          const float* __restrict__ bias,
                                          const u16* __restrict__ residb,
                                          u16* __restrict__ outb, int ostride,
                                          float* __restrict__ sum, float* __restrict__ sumsq,
                                          int slotbase, int m0, int K) {
    int tid = threadIdx.x;
    int lane = tid & 63, wave = tid >> 6;
    int wm = (wave & 1) * 64, wn = (wave >> 1) * 64;
    int l15 = lane & 15, l4 = lane >> 4;
    u16* Csw = Cs0 + wave * (16 * 72);

    if (STATS) {
        if (tid < 128) { csum[tid] = 0.f; csq[tid] = 0.f; }
    }

    f32x4 zero = {0.f, 0.f, 0.f, 0.f};
    f32x4 acc[4][4];
#pragma unroll
    for (int i = 0; i < 4; ++i)
#pragma unroll
        for (int j = 0; j < 4; ++j) acc[i][j] = zero;

    int srow = tid >> 2;
    int scol = (tid & 3) * 8;

    int kIter = K >> 5;
    uint4 a0 = *(const uint4*)(A + (size_t)(m0 + srow) * K + scol);
    uint4 a1 = *(const uint4*)(A + (size_t)(m0 + srow + 64) * K + scol);
    uint4 b0 = *(const uint4*)(W + (size_t)srow * K + scol);
    uint4 b1 = *(const uint4*)(W + (size_t)(srow + 64) * K + scol);
    for (int ki = 0; ki < kIter; ++ki) {
        if (ki) __syncthreads();
        *(uint4*)&As[srow * 32 + scol] = a0;
        *(uint4*)&As[(srow + 64) * 32 + scol] = a1;
        *(uint4*)&Bs[srow * 32 + scol] = b0;
        *(uint4*)&Bs[(srow + 64) * 32 + scol] = b1;
        if (ki + 1 < kIter) {
            int k0 = (ki + 1) * 32;
            a0 = *(const uint4*)(A + (size_t)(m0 + srow) * K + k0 + scol);
            a1 = *(const uint4*)(A + (size_t)(m0 + srow + 64) * K + k0 + scol);
            b0 = *(const uint4*)(W + (size_t)srow * K + k0 + scol);
            b1 = *(const uint4*)(W + (size_t)(srow + 64) * K + k0 + scol);
        }
        __syncthreads();
        short8 af[4], bf[4];
#pragma unroll
        for (int t = 0; t < 4; ++t) {
            af[t] = *(const short8*)&As[(wm + t * 16 + l15) * 32 + l4 * 8];
            bf[t] = *(const short8*)&Bs[(wn + t * 16 + l15) * 32 + l4 * 8];
        }
#pragma unroll
        for (int mt = 0; mt < 4; ++mt)
#pragma unroll
            for (int nt = 0; nt < 4; ++nt)
                acc[mt][nt] = __builtin_amdgcn_mfma_f32_16x16x32_bf16(af[mt], bf[nt], acc[mt][nt], 0, 0, 0);
    }

    float ps[4] = {0.f, 0.f, 0.f, 0.f};
    float pq[4] = {0.f, 0.f, 0.f, 0.f};
    int rl = lane >> 3;          // 0..7
    int cg = lane & 7;           // 0..7
#pragma unroll
    for (int mt = 0; mt < 4; ++mt) {
#pragma unroll
        for (int nt = 0; nt < 4; ++nt) {
            int lcol = wn + nt * 16 + l15;
            float bs = bias[lcol];
#pragma unroll
            for (int r = 0; r < 4; ++r) {
                int row = m0 + wm + mt * 16 + l4 * 4 + r;
                float v = acc[mt][nt][r] + bs;
                if (RESID == 2) v += b2f(residb[(size_t)row * 128 + lcol]);
                if (RELU) v = fmaxf(v, 0.0f);
                Csw[(l4 * 4 + r) * 72 + nt * 16 + l15] = f2b(v);
                if (STATS) { ps[nt] += v; pq[nt] += v * v; }
            }
        }
        // wide readback + coalesced store (wave-private, DS in-order: no barrier)
#pragma unroll
        for (int p = 0; p < 2; ++p) {
            int lrow = p * 8 + rl;
            uint4 wv = *(const uint4*)&Csw[lrow * 72 + cg * 8];
            int grow = m0 + wm + mt * 16 + lrow;
            *(uint4*)(outb + (size_t)grow * ostride + wn + cg * 8) = wv;
        }
    }
    if (STATS) {
#pragma unroll
        for (int nt = 0; nt < 4; ++nt) {
            atomicAdd(&csum[wn + nt * 16 + l15], ps[nt]);
            atomicAdd(&csq[wn + nt * 16 + l15], pq[nt]);
        }
        __syncthreads();
        if (tid < 128) {
            atomicAdd(sum + slotbase + tid, csum[tid]);
            atomicAdd(sumsq + slotbase + tid, csq[tid]);
        }
    }
}

// ---------------- QKV GEMM (standalone; runs between prep and the attn+gather fusion) ----------------
__global__ __launch_bounds__(256) void gemm_qkv(const u16* __restrict__ xb,
                                                const u16* __restrict__ Wqkvb,
                                                const float* __restrict__ bqs,
                                                u16* __restrict__ qkvb) {
    __shared__ GemmSmem sm;
    int y = blockIdx.y;
    gemm_body<false, 0, false>(sm.As, sm.Bs, &sm.Cs[0][0], sm.csum, sm.csq,
                               xb, Wqkvb + (size_t)y * 16384, bqs + y * 128, nullptr,
                               qkvb + y * 128, 384, nullptr, nullptr, 0, blockIdx.x * 128, 128);
}

// ---------------- fused: attention (bid<256) + gather-aggregate+Wc GEMM (bid>=256) ----------------
struct K3Smem {
    union {
        struct { u16 Ks[512 * 40]; u16 Vt[32 * 520]; } a;   // 72.5 KB attention
        GemmSmem g;                                          // 27.6 KB gather+Wc
    };
};

__global__ __launch_bounds__(256) void attn_gwc(const u16* __restrict__ qkv,
                                                u16* __restrict__ o,
                                                const int* __restrict__ bucket,
                                                const int* __restrict__ cursor,
                                                const u16* __restrict__ Wcb,
                                                const float* __restrict__ bc,
                                                const u16* __restrict__ xb,
                                                u16* __restrict__ aggb,
                                                u16* __restrict__ hlocb,
                                                float* __restrict__ sum1,
                                                float* __restrict__ sq1) {
    __shared__ __align__(16) K3Smem sm;
    int bid = blockIdx.x;
    int tid = threadIdx.x;

    if (bid < 256) {
        // ---- attention branch: 4 waves, each covers 128 q-rows (8 q-tiles).
        //      q is prescaled by scale*log2e -> softmax is a bare exp2; P packed via cvt_pk.
        u16* Ks = sm.a.Ks;
        u16* Vt = sm.a.Vt;
        int b = bid >> 2, h = bid & 3;
        int lane = tid & 63, wave = tid >> 6;
        int quad = lane >> 4, l15 = lane & 15;

        const u16* kvbase = qkv + (size_t)b * 512 * 384 + 128 + h * 32;
        for (int idx = tid; idx < 2048; idx += 256) {
            int row = idx >> 2, c = idx & 3;
            *(uint4*)&Ks[row * 40 + c * 8] = *(const uint4*)(kvbase + (size_t)row * 384 + c * 8);
        }
        for (int idx = tid; idx < 2048; idx += 256) {
            int row = idx >> 2, c = idx & 3;
            uint4 u = *(const uint4*)(kvbase + 128 + (size_t)row * 384 + c * 8);
            u16 e[8];
            *(uint4*)e = u;
#pragma unroll
            for (int i = 0; i < 8; ++i) Vt[(c * 8 + i) * 520 + row] = e[i];
        }
        __syncthreads();

        f32x4 zero = {0.f, 0.f, 0.f, 0.f};
        for (int qt = 0; qt < 8; ++qt) {
            int qbase = wave * 128 + qt * 16;
            short8 qf = *(const short8*)(qkv + (size_t)(b * 512 + qbase + l15) * 384 + h * 32 + quad * 8);
            float lq = 0.f;
            f32x4 oa[2] = {zero, zero};

            for (int kv0 = 0; kv0 < 512; kv0 += 64) {
                f32x4 s[4];
#pragma unroll
                for (int t = 0; t < 4; ++t) {
                    short8 kb = *(const short8*)&Ks[(kv0 + t * 16 + l15) * 40 + quad * 8];
                    s[t] = __builtin_amdgcn_mfma_f32_16x16x32_bf16(kb, qf, zero, 0, 0, 0);
                }
                // exp2 (scale folded into q) + packed bf16 convert; two 16-kv tiles per A-operand
                u32 ppw[2][4];
#pragma unroll
                for (int t = 0; t < 4; ++t) {
                    float p0 = EXP2(s[t][0]);
                    float p1 = EXP2(s[t][1]);
                    float p2 = EXP2(s[t][2]);
                    float p3 = EXP2(s[t][3]);
                    lq += (p0 + p1) + (p2 + p3);
                    ppw[t >> 1][(t & 1) * 2 + 0] = cvtpk(p0, p1);
                    ppw[t >> 1][(t & 1) * 2 + 1] = cvtpk(p2, p3);
                }
                short8 pps[2];
                pps[0] = *(const short8*)&ppw[0][0];
                pps[1] = *(const short8*)&ppw[1][0];
#pragma unroll
                for (int tp = 0; tp < 2; ++tp) {
                    int tb = kv0 + tp * 32;
#pragma unroll
                    for (int n = 0; n < 2; ++n) {
                        const u16* vrow = &Vt[(n * 16 + l15) * 520 + tb + quad * 4];
                        short4v va = *(const short4v*)vrow;          // kv tile 2tp
                        short4v vb2 = *(const short4v*)(vrow + 16);  // kv tile 2tp+1
                        short8 vv = {va.x, va.y, va.z, va.w, vb2.x, vb2.y, vb2.z, vb2.w};
                        oa[n] = __builtin_amdgcn_mfma_f32_16x16x32_bf16(pps[tp], vv, oa[n], 0, 0, 0);
                    }
                }
            }
            lq += __shfl_xor(lq, 16);
            lq += __shfl_xor(lq, 32);
            u16* op = o + (size_t)(b * 512 + qbase) * 128 + h * 32;
#pragma unroll
            for (int r = 0; r < 4; ++r) {
                float Lr = __shfl(lq, quad * 4 + r);
                float inv = 1.0f / Lr;
#pragma unroll
                for (int n = 0; n < 2; ++n)
                    op[(quad * 4 + r) * 128 + n * 16 + l15] = f2b(oa[n][r] * inv);
            }
        }
        return;
    }

    // ---- gather+Wc branch ----
    int m0 = (bid - 256) * 128;

    // phase 1: gather-aggregate this block's 128 nodes -> aggb (global; same-XCD L2 hit)
    {
        int (*srcs)[MAXDEG] = reinterpret_cast<int (*)[MAXDEG]>(sm.g.As);  // 6 KB overlay in As
        int ln = tid >> 4;     // node-in-pass 0..15
        int c8 = tid & 15;     // channel block of 8
        const u16* xp = xb + c8 * 8;
        for (int pass = 0; pass < 8; ++pass) {
            int n = pass * 16 + ln;          // local row 0..127
            int gn = m0 + n;
            int d = min(cursor[gn * CURPAD], MAXDEG);
            for (int j = c8; j < d; j += 16) srcs[ln][j] = bucket[gn * MAXDEG + j];
            __syncthreads();
            float s[8] = {0.f, 0.f, 0.f, 0.f, 0.f, 0.f, 0.f, 0.f};
            for (int base = 0; base < d; base += 8) {
                uint4 w[8];
#pragma unroll
                for (int u = 0; u < 8; ++u) {
                    int jj = base + u;
                    int idx = srcs[ln][jj < d ? jj : 0];
                    w[u] = *(const uint4*)(xp + (size_t)idx * CCH);
                }
#pragma unroll
                for (int u = 0; u < 8; ++u) {
                    if (base + u >= d) { w[u].x = 0; w[u].y = 0; w[u].z = 0; w[u].w = 0; }
                    s[0] += b2f(w[u].x & 0xffffu);
                    s[1] += b2f(w[u].x >> 16);
                    s[2] += b2f(w[u].y & 0xffffu);
                    s[3] += b2f(w[u].y >> 16);
                    s[4] += b2f(w[u].z & 0xffffu);
                    s[5] += b2f(w[u].z >> 16);
                    s[6] += b2f(w[u].w & 0xffffu);
                    s[7] += b2f(w[u].w >> 16);
                }
            }
            float inv = 1.0f / fmaxf((float)d, 1.0f);
            uint4 out;
            out.x = cvtpk(s[0] * inv, s[1] * inv);
            out.y = cvtpk(s[2] * inv, s[3] * inv);
            out.z = cvtpk(s[4] * inv, s[5] * inv);
            out.w = cvtpk(s[6] * inv, s[7] * inv);
            *(uint4*)(aggb + (size_t)gn * CCH + c8 * 8) = out;
            __syncthreads();   // srcs reused next pass
        }
    }
    __syncthreads();

    // phase 2: standard Wc GEMM, A = aggb (just written by this block -> L2-hot)
    gemm_body<false, 2, true>(sm.g.As, sm.g.Bs, &sm.g.Cs[0][0], sm.g.csum, sm.g.csq,
                              aggb, Wcb, bc, xb, hlocb, 128, sum1, sq1,
                              ((bid - 256) & (SSLOT - 1)) << 7, m0, 128);
}

// ---------------- Wo GEMM wrapper ----------------
__global__ __launch_bounds__(256) void gemm_wo(const u16* __restrict__ ob,
                                               const u16* __restrict__ Wob,
                                               const float* __restrict__ bo,
                                               const u16* __restrict__ xb,
                                               u16* __restrict__ t2b,
                                               float* __restrict__ sum2, float* __restrict__ sq2) {
    __shared__ GemmSmem sm;
    gemm_body<false, 2, true>(sm.As, sm.Bs, &sm.Cs[0][0], sm.csum, sm.csq,
                              ob, Wob, bo, xb, t2b, 128, sum2, sq2,
                              (blockIdx.x & (SSLOT - 1)) << 7, blockIdx.x * 128, 128);
}

// ---------------- MLP2 GEMM wrapper ----------------
__global__ __launch_bounds__(256) void gemm_mlp2(const u16* __restrict__ hidb,
                                                 const u16* __restrict__ Wm2b,
                                                 const float* __restrict__ bm2,
                                                 const u16* __restrict__ shb,
                                                 u16* __restrict__ out2b,
                                                 float* __restrict__ sum3, float* __restrict__ sq3) {
    __shared__ GemmSmem sm;
    gemm_body<false, 2, true>(sm.As, sm.Bs, &sm.Cs[0][0], sm.csum, sm.csq,
                              hidb, Wm2b, bm2, shb, out2b, 128, sum3, sq3,
                              (blockIdx.x & (SSLOT - 1)) << 7, blockIdx.x * 128, 256);
}

// ---------------- MLP1 GEMM with comb fused into A-staging; dbuf + wide stores ----------------
__global__ __launch_bounds__(256) void gemm_m1c(const u16* __restrict__ hlocb,
                                                const u16* __restrict__ t2b,
                                                const float* __restrict__ sum1,
                                                const float* __restrict__ sq1,
                                                const float* __restrict__ g1,
                                                const float* __restrict__ bt1,
                                                const float* __restrict__ sum2,
                                                const float* __restrict__ sq2,
                                                const float* __restrict__ g2,
                                                const float* __restrict__ bt2,
                                                u16* __restrict__ shb,
                                                const u16* __restrict__ Wm1b,
                                                const float* __restrict__ bm1,
                                                u16* __restrict__ hidb) {
    __shared__ u16 As[128 * 32];
    __shared__ u16 Bs[128 * 32];
    __shared__ u16 Cs[4][16 * 72];
    __shared__ float AF1[128], BF1[128], AF2[128], BF2[128];
    int tid = threadIdx.x;
    {
        int c = tid & 127;
        const float* sm = (tid < 128) ? sum1 : sum2;
        const float* sq = (tid < 128) ? sq1 : sq2;
        const float* g  = (tid < 128) ? g1 : g2;
        const float* bt = (tid < 128) ? bt1 : bt2;
        float s = 0.f, q = 0.f;
#pragma unroll
        for (int sl = 0; sl < SSLOT; ++sl) { s += sm[sl * 128 + c]; q += sq[sl * 128 + c]; }
        float m = s * (1.0f / NT);
        float v = q * (1.0f / NT) - m * m;
        float a = g[c] * rsqrtf(v + EPS);
        if (tid < 128) { AF1[c] = a; BF1[c] = bt[c] - m * a; }
        else           { AF2[c] = a; BF2[c] = bt[c] - m * a; }
    }
    int m0 = blockIdx.x * 128, n0 = blockIdx.y * 128;
    int lane = tid & 63, wave = tid >> 6;
    int wm = (wave & 1) * 64, wn = (wave >> 1) * 64;
    int l15 = lane & 15, l4 = lane >> 4;

    f32x4 zero = {0.f, 0.f, 0.f, 0.f};
    f32x4 acc[4][4];
#pragma unroll
    for (int i = 0; i < 4; ++i)
#pragma unroll
        for (int j = 0; j < 4; ++j) acc[i][j] = zero;

    int srow = tid >> 2;
    int scol = (tid & 3) * 8;
    bool wr = (blockIdx.y == 0);

    uint4 h0 = *(const uint4*)(hlocb + (size_t)(m0 + srow) * 128 + scol);
    uint4 h1 = *(const uint4*)(hlocb + (size_t)(m0 + srow + 64) * 128 + scol);
    uint4 t0 = *(const uint4*)(t2b + (size_t)(m0 + srow) * 128 + scol);
    uint4 t1 = *(const uint4*)(t2b + (size_t)(m0 + srow + 64) * 128 + scol);
    uint4 b0 = *(const uint4*)(Wm1b + (size_t)(n0 + srow) * 128 + scol);
    uint4 b1 = *(const uint4*)(Wm1b + (size_t)(n0 + srow + 64) * 128 + scol);
    // barrier for AF/BF shared arrays before first use
    __syncthreads();
    for (int ki = 0; ki < 4; ++ki) {
        int k0 = ki * 32;
        if (ki) __syncthreads();
        uint4 c0, c1;
        {
            const u32 hw[4] = {h0.x, h0.y, h0.z, h0.w};
            const u32 tw[4] = {t0.x, t0.y, t0.z, t0.w};
            u32 ow[4];
#pragma unroll
            for (int p = 0; p < 4; ++p) {
                int cc = k0 + scol + p * 2;
                float v0 = AF1[cc] * b2f(hw[p] & 0xffffu) + BF1[cc] + AF2[cc] * b2f(tw[p] & 0xffffu) + BF2[cc];
                float v1 = AF1[cc + 1] * b2f(hw[p] >> 16) + BF1[cc + 1] + AF2[cc + 1] * b2f(tw[p] >> 16) + BF2[cc + 1];
                ow[p] = cvtpk(v0, v1);
            }
            c0.x = ow[0]; c0.y = ow[1]; c0.z = ow[2]; c0.w = ow[3];
        }
        {
            const u32 hw[4] = {h1.x, h1.y, h1.z, h1.w};
            const u32 tw[4] = {t1.x, t1.y, t1.z, t1.w};
            u32 ow[4];
#pragma unroll
            for (int p = 0; p < 4; ++p) {
                int cc = k0 + scol + p * 2;
                float v0 = AF1[cc] * b2f(hw[p] & 0xffffu) + BF1[cc] + AF2[cc] * b2f(tw[p] & 0xffffu) + BF2[cc];
                float v1 = AF1[cc + 1] * b2f(hw[p] >> 16) + BF1[cc + 1] + AF2[cc + 1] * b2f(tw[p] >> 16) + BF2[cc + 1];
                ow[p] = cvtpk(v0, v1);
            }
            c1.x = ow[0]; c1.y = ow[1]; c1.z = ow[2]; c1.w = ow[3];
        }
        *(uint4*)&As[srow * 32 + scol] = c0;
        *(uint4*)&As[(srow + 64) * 32 + scol] = c1;
        *(uint4*)&Bs[srow * 32 + scol] = b0;
        *(uint4*)&Bs[(srow + 64) * 32 + scol] = b1;
        if (wr) {
            *(uint4*)(shb + (size_t)(m0 + srow) * 128 + k0 + scol) = c0;
            *(uint4*)(shb + (size_t)(m0 + srow + 64) * 128 + k0 + scol) = c1;
        }
        if (ki < 3) {
            int kn = k0 + 32;
            h0 = *(const uint4*)(hlocb + (size_t)(m0 + srow) * 128 + kn + scol);
            h1 = *(const uint4*)(hlocb + (size_t)(m0 + srow + 64) * 128 + kn + scol);
            t0 = *(const uint4*)(t2b + (size_t)(m0 + srow) * 128 + kn + scol);
            t1 = *(const uint4*)(t2b + (size_t)(m0 + srow + 64) * 128 + kn + scol);
            b0 = *(const uint4*)(Wm1b + (size_t)(n0 + srow) * 128 + kn + scol);
            b1 = *(const uint4*)(Wm1b + (size_t)(n0 + srow + 64) * 128 + kn + scol);
        }
        __syncthreads();
        short8 af[4], bf[4];
#pragma unroll
        for (int t = 0; t < 4; ++t) {
            af[t] = *(const short8*)&As[(wm + t * 16 + l15) * 32 + l4 * 8];
            bf[t] = *(const short8*)&Bs[(wn + t * 16 + l15) * 32 + l4 * 8];
        }
#pragma unroll
        for (int mt = 0; mt < 4; ++mt)
#pragma unroll
            for (int nt = 0; nt < 4; ++nt)
                acc[mt][nt] = __builtin_amdgcn_mfma_f32_16x16x32_bf16(af[mt], bf[nt], acc[mt][nt], 0, 0, 0);
    }

    int rl = lane >> 3;
    int cg = lane & 7;
#pragma unroll
    for (int mt = 0; mt < 4; ++mt) {
#pragma unroll
        for (int nt = 0; nt < 4; ++nt) {
            int col = n0 + wn + nt * 16 + l15;
            float bs = bm1[col];
#pragma unroll
            for (int r = 0; r < 4; ++r) {
                float v = fmaxf(acc[mt][nt][r] + bs, 0.0f);
                Cs[wave][(l4 * 4 + r) * 72 + nt * 16 + l15] = f2b(v);
            }
        }
#pragma unroll
        for (int p = 0; p < 2; ++p) {
            int lrow = p * 8 + rl;
            uint4 wv = *(const uint4*)&Cs[wave][lrow * 72 + cg * 8];
            int grow = m0 + wm + mt * 16 + lrow;
            *(uint4*)(hidb + (size_t)grow * 256 + n0 + wn + cg * 8) = wv;
        }
    }
}

// ---------------- final = bn3(out2), affine in-block, bf16 -> fp32 ----------------
__global__ __launch_bounds__(256) void final_bn(const u16* __restrict__ X,
                                                const float* __restrict__ sum3,
                                                const float* __restrict__ sq3,
                                                const float* __restrict__ g3,
                                                const float* __restrict__ bt3,
                                                float* __restrict__ outp) {
    __shared__ float A3[128], B3[128];
    int t = threadIdx.x;
    if (t < 128) {
        float s = 0.f, q = 0.f;
#pragma unroll
        for (int sl = 0; sl < SSLOT; ++sl) { s += sum3[sl * 128 + t]; q += sq3[sl * 128 + t]; }
        float m = s * (1.0f / NT);
        float v = q * (1.0f / NT) - m * m;
        float a = g3[t] * rsqrtf(v + EPS);
        A3[t] = a;
        B3[t] = bt3[t] - m * a;
    }
    __syncthreads();
    int i8 = blockIdx.x * 256 + t;
    size_t i = (size_t)i8 * 8;
    int c = (int)(i & (CCH - 1));
    uint4 u = *(const uint4*)(X + i);
    float x[8];
    x[0] = b2f(u.x & 0xffffu); x[1] = b2f(u.x >> 16);
    x[2] = b2f(u.y & 0xffffu); x[3] = b2f(u.y >> 16);
    x[4] = b2f(u.z & 0xffffu); x[5] = b2f(u.z >> 16);
    x[6] = b2f(u.w & 0xffffu); x[7] = b2f(u.w >> 16);
    float4 o0, o1;
    o0.x = A3[c + 0] * x[0] + B3[c + 0];
    o0.y = A3[c + 1] * x[1] + B3[c + 1];
    o0.z = A3[c + 2] * x[2] + B3[c + 2];
    o0.w = A3[c + 3] * x[3] + B3[c + 3];
    o1.x = A3[c + 4] * x[4] + B3[c + 4];
    o1.y = A3[c + 5] * x[5] + B3[c + 5];
    o1.z = A3[c + 6] * x[6] + B3[c + 6];
    o1.w = A3[c + 7] * x[7] + B3[c + 7];
    *(float4*)(outp + i) = o0;
    *(float4*)(outp + i + 4) = o1;
}

extern "C" void kernel_launch(void* const* d_in, const int* in_sizes, int n_in,
                              void* d_out, int out_size, void* d_ws, size_t ws_size,
                              hipStream_t stream) {
    const float* x    = (const float*)d_in[0];
    const int*   ei   = (const int*)d_in[1];
    const float* Wc   = (const float*)d_in[2];
    const float* bc   = (const float*)d_in[3];
    const float* Wqkv = (const float*)d_in[4];
    const float* bqkv = (const float*)d_in[5];
    const float* Wo   = (const float*)d_in[6];
    const float* bo   = (const float*)d_in[7];
    const float* gn1  = (const float*)d_in[8];
    const float* bn1b = (const float*)d_in[9];
    const float* gn2  = (const float*)d_in[10];
    const float* bn2b = (const float*)d_in[11];
    const float* gn3  = (const float*)d_in[12];
    const float* bn3b = (const float*)d_in[13];
    const float* Wm1  = (const float*)d_in[14];
    const float* bm1  = (const float*)d_in[15];
    const float* Wm2  = (const float*)d_in[16];
    const float* bm2  = (const float*)d_in[17];
    float* outp = (float*)d_out;

    char* w = (char*)d_ws;
    const size_t MB = 1024 * 1024;
    u16* xb    = (u16*)(w);                     //  8 MB
    u16* hlocb = (u16*)(w + 8 * MB);            //  8 MB
    u16* t2b   = (u16*)(w + 16 * MB);           //  8 MB  h_attn
    u16* out2b = (u16*)(w + 24 * MB);           //  8 MB
    u16* qkvb  = (u16*)(w + 32 * MB);           // 24 MB
    u16* hidb  = (u16*)(w + 56 * MB);           // 16 MB  [NT,256]
    u16* shb   = (u16*)(w + 72 * MB);           //  8 MB  aggb -> comb
    int* bucket = (int*)(w + 80 * MB);          // 12 MB
    int* cursor = (int*)(w + 92 * MB);          //  2 MB (padded: 1 counter / 64B line)
    float* stats = (float*)(w + 94 * MB);       //  stats (6x1024 floats) + bqs (384 floats)
    u16* Wcb   = (u16*)(w + 95 * MB);
    u16* Wqkvb = Wcb + 16384;
    u16* Wob   = Wqkvb + 49152;
    u16* Wm1b  = Wob + 16384;
    u16* Wm2b  = Wm1b + 32768;
    u16* ob    = (u16*)(w + 96 * MB);           //  8 MB  attention output (own buffer)
    float* sum1 = stats;                  float* sq1 = stats + 1024;
    float* sum2 = stats + 2048;           float* sq2 = stats + 3072;
    float* sum3 = stats + 4096;           float* sq3 = stats + 5120;
    float* bqs  = stats + 6144;           // prescaled qkv bias (384 floats)

    // cursor (2 MB) and stats+bqs (contiguous) in one memset
    hipMemsetAsync(cursor, 0, 2 * MB + 7 * 1024 * 4, stream);

    // conv (blocks 0..2119) + bias prescale (2120) + XCD-partitioned fill (2128..4175); LDS = 0
    prep_kernel<<<FILL0 + 2048, 256, 0, stream>>>(x, Wc, Wqkv, Wo, Wm1, Wm2,
                                                  xb, Wcb, Wqkvb, Wob, Wm1b, Wm2b,
                                                  bqkv, bqs, ei, cursor, bucket);

    {
        dim3 g(NT / 128, 3);
        gemm_qkv<<<g, 256, 0, stream>>>(xb, Wqkvb, bqs, qkvb);
    }

    // fused: attention (256 blocks) co-scheduled with gather+Wc (256 blocks)
    attn_gwc<<<512, 256, 0, stream>>>(qkvb, ob, bucket, cursor, Wcb, bc, xb,
                                      shb /*aggb*/, hlocb, sum1, sq1);

    gemm_wo<<<NT / 128, 256, 0, stream>>>(ob, Wob, bo, xb, t2b, sum2, sq2);

    {
        dim3 g(NT / 128, 2);
        gemm_m1c<<<g, 256, 0, stream>>>(hlocb, t2b, sum1, sq1, gn1, bn1b,
                                        sum2, sq2, gn2, bn2b, shb, Wm1b, bm1, hidb);
    }

    gemm_mlp2<<<NT / 128, 256, 0, stream>>>(hidb, Wm2b, bm2, shb, out2b, sum3, sq3);

    final_bn<<<NT * CCH / 8 / 256, 256, 0, stream>>>(out2b, sum3, sq3, gn3, bn3b, outp);
}

// Round 12
// 210.564 us; speedup vs baseline: 1.0671x; 1.0453x over previous
//
#include <hip/hip_runtime.h>
#include <cstddef>

#define NT    32768
#define CCH   128
#define BB    64
#define NNODE 512
#define NHEAD 4
#define DHEAD 32
#define EE    524288
#define EPS   1e-5f
#define MAXDEG 96
#define CURPAD 16      // one cursor counter per 64B cache line
#define SSLOT  8       // stats atomic spreading slots
#define EGRP  2048     // edges per partition group (E / 256 groups)
#define FILL0 2128     // first fill block (8-aligned so (bid-FILL0)&7 == bid&7)

typedef unsigned short u16;
typedef unsigned int   u32;
typedef __attribute__((ext_vector_type(8))) short short8;
typedef __attribute__((ext_vector_type(4))) short short4v;
typedef __attribute__((ext_vector_type(4))) float f32x4;

__device__ __forceinline__ float b2f(u32 w) { return __uint_as_float(w << 16); }
__device__ __forceinline__ u16 f2b(float f) {
    u32 u = __float_as_uint(f);
    u += 0x7FFF + ((u >> 16) & 1);   // RNE
    return (u16)(u >> 16);
}
// packed f32x2 -> bf16x2 (RNE), single instruction; no builtin on gfx950 (guide T12)
__device__ __forceinline__ u32 cvtpk(float lo, float hi) {
    u32 r;
    asm("v_cvt_pk_bf16_f32 %0, %1, %2" : "=v"(r) : "v"(lo), "v"(hi));
    return r;
}
#if __has_builtin(__builtin_amdgcn_exp2f)
#define EXP2(x) __builtin_amdgcn_exp2f(x)
#else
#define EXP2(x) exp2f(x)
#endif
// softmax scale (1/sqrt(32)) * log2(e), folded into Wq/bq at conversion time
#define SCLOG2E (0.1767766952966369f * 1.4426950408889634f)

// ---------------- prep: bf16 conversion (Wq/bq prescaled) + XCD-partitioned bucket fill ------------
// NO __shared__: fill blocks need max occupancy (8 blocks/CU) for atomic/scatter TLP (round-10 lesson).
__global__ __launch_bounds__(256) void prep_kernel(const float* __restrict__ x,
                                                   const float* __restrict__ Wc,
                                                   const float* __restrict__ Wqkv,
                                                   const float* __restrict__ Wo,
                                                   const float* __restrict__ Wm1,
                                                   const float* __restrict__ Wm2,
                                                   u16* __restrict__ xb,
                                                   u16* __restrict__ Wcb,
                                                   u16* __restrict__ Wqkvb,
                                                   u16* __restrict__ Wob,
                                                   u16* __restrict__ Wm1b,
                                                   u16* __restrict__ Wm2b,
                                                   const float* __restrict__ bqkv,
                                                   float* __restrict__ bqs,
                                                   const int* __restrict__ ei,
                                                   int* __restrict__ cursor,
                                                   int* __restrict__ bucket) {
    int bid = blockIdx.x;
    if (bid >= FILL0) {
        int b2 = bid - FILL0;
        int k = b2 & 7;
        int g = b2 >> 3;
        int base_e = g * EGRP;
        for (int j = threadIdx.x; j < EGRP; j += 256) {
            int dst = ei[EE + base_e + j];
            if ((dst & 7) == k) {
                int src = ei[base_e + j];
                int pos = atomicAdd(cursor + dst * CURPAD, 1);
                if (pos < MAXDEG) bucket[dst * MAXDEG + pos] = src;
            }
        }
        return;
    }
    if (bid == 2120) {
        int t = threadIdx.x;
        if (t < 384) {
            float v = bqkv[t];
            if (t < 128) v *= SCLOG2E;
            bqs[t] = v;
        }
        return;
    }
    if (bid > 2120) return;   // 2121..2127 idle (alignment padding)
    int r = bid * 256 + threadIdx.x;
    const float* src; u16* dst; float qs = 1.0f;
    if (r < 524288) { src = x; dst = xb; }
    else if ((r -= 524288) < 2048) { src = Wc; dst = Wcb; }
    else if ((r -= 2048) < 6144) { src = Wqkv; dst = Wqkvb; if (r < 2048) qs = SCLOG2E; }
    else if ((r -= 6144) < 2048) { src = Wo; dst = Wob; }
    else if ((r -= 2048) < 4096) { src = Wm1; dst = Wm1b; }
    else { r -= 4096; src = Wm2; dst = Wm2b; }
    size_t base = (size_t)r * 8;
    float4 a = *(const float4*)(src + base);
    float4 b = *(const float4*)(src + base + 4);
    uint4 u;
    u.x = cvtpk(a.x * qs, a.y * qs);
    u.y = cvtpk(a.z * qs, a.w * qs);
    u.z = cvtpk(b.x * qs, b.y * qs);
    u.w = cvtpk(b.z * qs, b.w * qs);
    *(uint4*)(dst + base) = u;
}

// ---------------- shared GEMM smem + body: 128x128 tile, dbuf + wide stores (27.6 KB) ----------------
struct GemmSmem {
    u16 As[128 * 32];
    u16 Bs[128 * 32];
    u16 Cs[4][16 * 72];
    float csum[128];
    float csq[128];
};

// outb pre-offset to column 0 of this GEMM's output slice; ostride = its row stride.
// bias/residb indexed by LOCAL column (0..127); residb row stride = 128.
template <bool RELU, int RESID, bool STATS>
__device__ __forceinline__ void gemm_body(u16* __restrict__ As, u16* __restrict__ Bs,
                                          u16* __restrict__ Cs0, float* __restrict__ csum,
                                          float* __restrict__ csq,
                                          const u16* __restrict__ A,
                                          const u16* __restrict__ W,
                                          const float* __restrict__ bias,
                                          const u16* __restrict__ residb,
                                          u16* __restrict__ outb, int ostride,
                                          float* __restrict__ sum, float* __restrict__ sumsq,
                                          int slotbase, int m0, int K) {
    int tid = threadIdx.x;
    int lane = tid & 63, wave = tid >> 6;
    int wm = (wave & 1) * 64, wn = (wave >> 1) * 64;
    int l15 = lane & 15, l4 = lane >> 4;
    u16* Csw = Cs0 + wave * (16 * 72);

    if (STATS) {
        if (tid < 128) { csum[tid] = 0.f; csq[tid] = 0.f; }
    }

    f32x4 zero = {0.f, 0.f, 0.f, 0.f};
    f32x4 acc[4][4];
#pragma unroll
    for (int i = 0; i < 4; ++i)
#pragma unroll
        for (int j = 0; j < 4; ++j) acc[i][j] = zero;

    int srow = tid >> 2;
    int scol = (tid & 3) * 8;

    int kIter = K >> 5;
    uint4 a0 = *(const uint4*)(A + (size_t)(m0 + srow) * K + scol);
    uint4 a1 = *(const uint4*)(A + (size_t)(m0 + srow + 64) * K + scol);
    uint4 b0 = *(const uint4*)(W + (size_t)srow * K + scol);
    uint4 b1 = *(const uint4*)(W + (size_t)(srow + 64) * K + scol);
    for (int ki = 0; ki < kIter; ++ki) {
        if (ki) __syncthreads();
        *(uint4*)&As[srow * 32 + scol] = a0;
        *(uint4*)&As[(srow + 64) * 32 + scol] = a1;
        *(uint4*)&Bs[srow * 32 + scol] = b0;
        *(uint4*)&Bs[(srow + 64) * 32 + scol] = b1;
        if (ki + 1 < kIter) {
            int k0 = (ki + 1) * 32;
            a0 = *(const uint4*)(A + (size_t)(m0 + srow) * K + k0 + scol);
            a1 = *(const uint4*)(A + (size_t)(m0 + srow + 64) * K + k0 + scol);
            b0 = *(const uint4*)(W + (size_t)srow * K + k0 + scol);
            b1 = *(const uint4*)(W + (size_t)(srow + 64) * K + k0 + scol);
        }
        __syncthreads();
        short8 af[4], bf[4];
#pragma unroll
        for (int t = 0; t < 4; ++t) {
            af[t] = *(const short8*)&As[(wm + t * 16 + l15) * 32 + l4 * 8];
            bf[t] = *(const short8*)&Bs[(wn + t * 16 + l15) * 32 + l4 * 8];
        }
#pragma unroll
        for (int mt = 0; mt < 4; ++mt)
#pragma unroll
            for (int nt = 0; nt < 4; ++nt)
                acc[mt][nt] = __builtin_amdgcn_mfma_f32_16x16x32_bf16(af[mt], bf[nt], acc[mt][nt], 0, 0, 0);
    }

    float ps[4] = {0.f, 0.f, 0.f, 0.f};
    float pq[4] = {0.f, 0.f, 0.f, 0.f};
    int rl = lane >> 3;          // 0..7
    int cg = lane & 7;           // 0..7
#pragma unroll
    for (int mt = 0; mt < 4; ++mt) {
#pragma unroll
        for (int nt = 0; nt < 4; ++nt) {
            int lcol = wn + nt * 16 + l15;
            float bs = bias[lcol];
#pragma unroll
            for (int r = 0; r < 4; ++r) {
                int row = m0 + wm + mt * 16 + l4 * 4 + r;
                float v = acc[mt][nt][r] + bs;
                if (RESID == 2) v += b2f(residb[(size_t)row * 128 + lcol]);
                if (RELU) v = fmaxf(v, 0.0f);
                Csw[(l4 * 4 + r) * 72 + nt * 16 + l15] = f2b(v);
                if (STATS) { ps[nt] += v; pq[nt] += v * v; }
            }
        }
        // wide readback + coalesced store (wave-private, DS in-order: no barrier)
#pragma unroll
        for (int p = 0; p < 2; ++p) {
            int lrow = p * 8 + rl;
            uint4 wv = *(const uint4*)&Csw[lrow * 72 + cg * 8];
            int grow = m0 + wm + mt * 16 + lrow;
            *(uint4*)(outb + (size_t)grow * ostride + wn + cg * 8) = wv;
        }
    }
    if (STATS) {
#pragma unroll
        for (int nt = 0; nt < 4; ++nt) {
            atomicAdd(&csum[wn + nt * 16 + l15], ps[nt]);
            atomicAdd(&csq[wn + nt * 16 + l15], pq[nt]);
        }
        __syncthreads();
        if (tid < 128) {
            atomicAdd(sum + slotbase + tid, csum[tid]);
            atomicAdd(sumsq + slotbase + tid, csq[tid]);
        }
    }
}

// ---------------- QKV GEMM (standalone; runs between prep and the attn+gather fusion) ----------------
__global__ __launch_bounds__(256) void gemm_qkv(const u16* __restrict__ xb,
                                                const u16* __restrict__ Wqkvb,
                                                const float* __restrict__ bqs,
                                                u16* __restrict__ qkvb) {
    __shared__ GemmSmem sm;
    int y = blockIdx.y;
    gemm_body<false, 0, false>(sm.As, sm.Bs, &sm.Cs[0][0], sm.csum, sm.csq,
                               xb, Wqkvb + (size_t)y * 16384, bqs + y * 128, nullptr,
                               qkvb + y * 128, 384, nullptr, nullptr, 0, blockIdx.x * 128, 128);
}

// ---------------- fused: attention (bid<256, 8 waves) + gather (bid>=256, 8 waves) ----------------
// 512-thread blocks: 2 blocks/CU (74KB LDS) -> 16 waves/CU. Gather gets 8 waves (2x round-11's 4)
// both during attn co-residency and after; Wc GEMM moved out (fused with Wo) so the gather branch
// is pure gather.
struct AGSmem {
    union {
        struct { u16 Ks[512 * 40]; u16 Vt[32 * 520]; } a;   // 72.5 KB attention
        int srcs[32][MAXDEG];                                // 12 KB gather
    };
};

__global__ __launch_bounds__(512) void attn_gath(const u16* __restrict__ qkv,
                                                 u16* __restrict__ o,
                                                 const int* __restrict__ bucket,
                                                 const int* __restrict__ cursor,
                                                 const u16* __restrict__ xb,
                                                 u16* __restrict__ aggb) {
    __shared__ __align__(16) AGSmem sm;
    int bid = blockIdx.x;
    int tid = threadIdx.x;

    if (bid < 256) {
        // ---- attention branch: 8 waves, 4 q-tiles each (round-6 structure + VALU slimming) ----
        u16* Ks = sm.a.Ks;
        u16* Vt = sm.a.Vt;
        int b = bid >> 2, h = bid & 3;
        int lane = tid & 63, wave = tid >> 6;
        int quad = lane >> 4, l15 = lane & 15;

        const u16* kvbase = qkv + (size_t)b * 512 * 384 + 128 + h * 32;
        for (int idx = tid; idx < 2048; idx += 512) {
            int row = idx >> 2, c = idx & 3;
            *(uint4*)&Ks[row * 40 + c * 8] = *(const uint4*)(kvbase + (size_t)row * 384 + c * 8);
        }
        for (int idx = tid; idx < 2048; idx += 512) {
            int row = idx >> 2, c = idx & 3;
            uint4 u = *(const uint4*)(kvbase + 128 + (size_t)row * 384 + c * 8);
            u16 e[8];
            *(uint4*)e = u;
#pragma unroll
            for (int i = 0; i < 8; ++i) Vt[(c * 8 + i) * 520 + row] = e[i];
        }
        __syncthreads();

        f32x4 zero = {0.f, 0.f, 0.f, 0.f};
        for (int qt = 0; qt < 4; ++qt) {
            int qbase = wave * 64 + qt * 16;
            short8 qf = *(const short8*)(qkv + (size_t)(b * 512 + qbase + l15) * 384 + h * 32 + quad * 8);
            float lq = 0.f;
            f32x4 oa[2] = {zero, zero};

            for (int kv0 = 0; kv0 < 512; kv0 += 64) {
                f32x4 s[4];
#pragma unroll
                for (int t = 0; t < 4; ++t) {
                    short8 kb = *(const short8*)&Ks[(kv0 + t * 16 + l15) * 40 + quad * 8];
                    s[t] = __builtin_amdgcn_mfma_f32_16x16x32_bf16(kb, qf, zero, 0, 0, 0);
                }
                // exp2 (scale folded into q) + packed bf16 convert; two 16-kv tiles per A-operand
                u32 ppw[2][4];
#pragma unroll
                for (int t = 0; t < 4; ++t) {
                    float p0 = EXP2(s[t][0]);
                    float p1 = EXP2(s[t][1]);
                    float p2 = EXP2(s[t][2]);
                    float p3 = EXP2(s[t][3]);
                    lq += (p0 + p1) + (p2 + p3);
                    ppw[t >> 1][(t & 1) * 2 + 0] = cvtpk(p0, p1);
                    ppw[t >> 1][(t & 1) * 2 + 1] = cvtpk(p2, p3);
                }
                short8 pps[2];
                pps[0] = *(const short8*)&ppw[0][0];
                pps[1] = *(const short8*)&ppw[1][0];
#pragma unroll
                for (int tp = 0; tp < 2; ++tp) {
                    int tb = kv0 + tp * 32;
#pragma unroll
                    for (int n = 0; n < 2; ++n) {
                        const u16* vrow = &Vt[(n * 16 + l15) * 520 + tb + quad * 4];
                        short4v va = *(const short4v*)vrow;          // kv tile 2tp
                        short4v vb2 = *(const short4v*)(vrow + 16);  // kv tile 2tp+1
                        short8 vv = {va.x, va.y, va.z, va.w, vb2.x, vb2.y, vb2.z, vb2.w};
                        oa[n] = __builtin_amdgcn_mfma_f32_16x16x32_bf16(pps[tp], vv, oa[n], 0, 0, 0);
                    }
                }
            }
            lq += __shfl_xor(lq, 16);
            lq += __shfl_xor(lq, 32);
            u16* op = o + (size_t)(b * 512 + qbase) * 128 + h * 32;
#pragma unroll
            for (int r = 0; r < 4; ++r) {
                float Lr = __shfl(lq, quad * 4 + r);
                float inv = 1.0f / Lr;
#pragma unroll
                for (int n = 0; n < 2; ++n)
                    op[(quad * 4 + r) * 128 + n * 16 + l15] = f2b(oa[n][r] * inv);
            }
        }
        return;
    }

    // ---- pure gather branch: 128 nodes/block, 32 node-groups x 16 ch-lanes, 8-deep batching ----
    {
        int m0 = (bid - 256) * 128;
        int ln = tid >> 4;     // node-in-pass 0..31
        int c8 = tid & 15;     // channel block of 8
        const u16* xp = xb + c8 * 8;
        for (int pass = 0; pass < 4; ++pass) {
            int n = pass * 32 + ln;          // local row 0..127
            int gn = m0 + n;
            int d = min(cursor[gn * CURPAD], MAXDEG);
            for (int j = c8; j < d; j += 16) sm.srcs[ln][j] = bucket[gn * MAXDEG + j];
            __syncthreads();
            float s[8] = {0.f, 0.f, 0.f, 0.f, 0.f, 0.f, 0.f, 0.f};
            for (int base = 0; base < d; base += 8) {
                uint4 w[8];
#pragma unroll
                for (int u = 0; u < 8; ++u) {
                    int jj = base + u;
                    int idx = sm.srcs[ln][jj < d ? jj : 0];
                    w[u] = *(const uint4*)(xp + (size_t)idx * CCH);
                }
#pragma unroll
                for (int u = 0; u < 8; ++u) {
                    if (base + u >= d) { w[u].x = 0; w[u].y = 0; w[u].z = 0; w[u].w = 0; }
                    s[0] += b2f(w[u].x & 0xffffu);
                    s[1] += b2f(w[u].x >> 16);
                    s[2] += b2f(w[u].y & 0xffffu);
                    s[3] += b2f(w[u].y >> 16);
                    s[4] += b2f(w[u].z & 0xffffu);
                    s[5] += b2f(w[u].z >> 16);
                    s[6] += b2f(w[u].w & 0xffffu);
                    s[7] += b2f(w[u].w >> 16);
                }
            }
            float inv = 1.0f / fmaxf((float)d, 1.0f);
            uint4 out;
            out.x = cvtpk(s[0] * inv, s[1] * inv);
            out.y = cvtpk(s[2] * inv, s[3] * inv);
            out.z = cvtpk(s[4] * inv, s[5] * inv);
            out.w = cvtpk(s[6] * inv, s[7] * inv);
            *(uint4*)(aggb + (size_t)gn * CCH + c8 * 8) = out;
            __syncthreads();   // srcs reused next pass
        }
    }
}

// ---------------- fused dual GEMM: y=0 Wc (h_local <- aggb), y=1 Wo (h_attn <- ob) ----------------
__global__ __launch_bounds__(256) void gemm_wc_wo(const u16* __restrict__ aggb,
                                                  const u16* __restrict__ Wcb,
                                                  const float* __restrict__ bc,
                                                  const u16* __restrict__ ob,
                                                  const u16* __restrict__ Wob,
                                                  const float* __restrict__ bo,
                                                  const u16* __restrict__ xb,
                                                  u16* __restrict__ hlocb,
                                                  u16* __restrict__ t2b,
                                                  float* __restrict__ sum1, float* __restrict__ sq1,
                                                  float* __restrict__ sum2, float* __restrict__ sq2) {
    __shared__ GemmSmem sm;
    bool wo = (blockIdx.y != 0);
    int m0 = blockIdx.x * 128;
    int slotbase = (blockIdx.x & (SSLOT - 1)) << 7;
    gemm_body<false, 2, true>(sm.As, sm.Bs, &sm.Cs[0][0], sm.csum, sm.csq,
                              wo ? ob : aggb,
                              wo ? Wob : Wcb,
                              wo ? bo : bc,
                              xb,
                              wo ? t2b : hlocb, 128,
                              wo ? sum2 : sum1,
                              wo ? sq2 : sq1,
                              slotbase, m0, 128);
}

// ---------------- MLP2 GEMM wrapper ----------------
__global__ __launch_bounds__(256) void gemm_mlp2(const u16* __restrict__ hidb,
                                                 const u16* __restrict__ Wm2b,
                                                 const float* __restrict__ bm2,
                                                 const u16* __restrict__ shb,
                                                 u16* __restrict__ out2b,
                                                 float* __restrict__ sum3, float* __restrict__ sq3) {
    __shared__ GemmSmem sm;
    gemm_body<false, 2, true>(sm.As, sm.Bs, &sm.Cs[0][0], sm.csum, sm.csq,
                              hidb, Wm2b, bm2, shb, out2b, 128, sum3, sq3,
                              (blockIdx.x & (SSLOT - 1)) << 7, blockIdx.x * 128, 256);
}

// ---------------- MLP1 GEMM with comb fused into A-staging; dbuf + wide stores ----------------
__global__ __launch_bounds__(256) void gemm_m1c(const u16* __restrict__ hlocb,
                                                const u16* __restrict__ t2b,
                                                const float* __restrict__ sum1,
                                                const float* __restrict__ sq1,
                                                const float* __restrict__ g1,
                                                const float* __restrict__ bt1,
                                                const float* __restrict__ sum2,
                                                const float* __restrict__ sq2,
                                                const float* __restrict__ g2,
                                                const float* __restrict__ bt2,
                                                u16* __restrict__ shb,
                                                const u16* __restrict__ Wm1b,
                                                const float* __restrict__ bm1,
                                                u16* __restrict__ hidb) {
    __shared__ u16 As[128 * 32];
    __shared__ u16 Bs[128 * 32];
    __shared__ u16 Cs[4][16 * 72];
    __shared__ float AF1[128], BF1[128], AF2[128], BF2[128];
    int tid = threadIdx.x;
    {
        int c = tid & 127;
        const float* sm = (tid < 128) ? sum1 : sum2;
        const float* sq = (tid < 128) ? sq1 : sq2;
        const float* g  = (tid < 128) ? g1 : g2;
        const float* bt = (tid < 128) ? bt1 : bt2;
        float s = 0.f, q = 0.f;
#pragma unroll
        for (int sl = 0; sl < SSLOT; ++sl) { s += sm[sl * 128 + c]; q += sq[sl * 128 + c]; }
        float m = s * (1.0f / NT);
        float v = q * (1.0f / NT) - m * m;
        float a = g[c] * rsqrtf(v + EPS);
        if (tid < 128) { AF1[c] = a; BF1[c] = bt[c] - m * a; }
        else           { AF2[c] = a; BF2[c] = bt[c] - m * a; }
    }
    int m0 = blockIdx.x * 128, n0 = blockIdx.y * 128;
    int lane = tid & 63, wave = tid >> 6;
    int wm = (wave & 1) * 64, wn = (wave >> 1) * 64;
    int l15 = lane & 15, l4 = lane >> 4;

    f32x4 zero = {0.f, 0.f, 0.f, 0.f};
    f32x4 acc[4][4];
#pragma unroll
    for (int i = 0; i < 4; ++i)
#pragma unroll
        for (int j = 0; j < 4; ++j) acc[i][j] = zero;

    int srow = tid >> 2;
    int scol = (tid & 3) * 8;
    bool wr = (blockIdx.y == 0);

    uint4 h0 = *(const uint4*)(hlocb + (size_t)(m0 + srow) * 128 + scol);
    uint4 h1 = *(const uint4*)(hlocb + (size_t)(m0 + srow + 64) * 128 + scol);
    uint4 t0 = *(const uint4*)(t2b + (size_t)(m0 + srow) * 128 + scol);
    uint4 t1 = *(const uint4*)(t2b + (size_t)(m0 + srow + 64) * 128 + scol);
    uint4 b0 = *(const uint4*)(Wm1b + (size_t)(n0 + srow) * 128 + scol);
    uint4 b1 = *(const uint4*)(Wm1b + (size_t)(n0 + srow + 64) * 128 + scol);
    // barrier for AF/BF shared arrays before first use
    __syncthreads();
    for (int ki = 0; ki < 4; ++ki) {
        int k0 = ki * 32;
        if (ki) __syncthreads();
        uint4 c0, c1;
        {
            const u32 hw[4] = {h0.x, h0.y, h0.z, h0.w};
            const u32 tw[4] = {t0.x, t0.y, t0.z, t0.w};
            u32 ow[4];
#pragma unroll
            for (int p = 0; p < 4; ++p) {
                int cc = k0 + scol + p * 2;
                float v0 = AF1[cc] * b2f(hw[p] & 0xffffu) + BF1[cc] + AF2[cc] * b2f(tw[p] & 0xffffu) + BF2[cc];
                float v1 = AF1[cc + 1] * b2f(hw[p] >> 16) + BF1[cc + 1] + AF2[cc + 1] * b2f(tw[p] >> 16) + BF2[cc + 1];
                ow[p] = cvtpk(v0, v1);
            }
            c0.x = ow[0]; c0.y = ow[1]; c0.z = ow[2]; c0.w = ow[3];
        }
        {
            const u32 hw[4] = {h1.x, h1.y, h1.z, h1.w};
            const u32 tw[4] = {t1.x, t1.y, t1.z, t1.w};
            u32 ow[4];
#pragma unroll
            for (int p = 0; p < 4; ++p) {
                int cc = k0 + scol + p * 2;
                float v0 = AF1[cc] * b2f(hw[p] & 0xffffu) + BF1[cc] + AF2[cc] * b2f(tw[p] & 0xffffu) + BF2[cc];
                float v1 = AF1[cc + 1] * b2f(hw[p] >> 16) + BF1[cc + 1] + AF2[cc + 1] * b2f(tw[p] >> 16) + BF2[cc + 1];
                ow[p] = cvtpk(v0, v1);
            }
            c1.x = ow[0]; c1.y = ow[1]; c1.z = ow[2]; c1.w = ow[3];
        }
        *(uint4*)&As[srow * 32 + scol] = c0;
        *(uint4*)&As[(srow + 64) * 32 + scol] = c1;
        *(uint4*)&Bs[srow * 32 + scol] = b0;
        *(uint4*)&Bs[(srow + 64) * 32 + scol] = b1;
        if (wr) {
            *(uint4*)(shb + (size_t)(m0 + srow) * 128 + k0 + scol) = c0;
            *(uint4*)(shb + (size_t)(m0 + srow + 64) * 128 + k0 + scol) = c1;
        }
        if (ki < 3) {
            int kn = k0 + 32;
            h0 = *(const uint4*)(hlocb + (size_t)(m0 + srow) * 128 + kn + scol);
            h1 = *(const uint4*)(hlocb + (size_t)(m0 + srow + 64) * 128 + kn + scol);
            t0 = *(const uint4*)(t2b + (size_t)(m0 + srow) * 128 + kn + scol);
            t1 = *(const uint4*)(t2b + (size_t)(m0 + srow + 64) * 128 + kn + scol);
            b0 = *(const uint4*)(Wm1b + (size_t)(n0 + srow) * 128 + kn + scol);
            b1 = *(const uint4*)(Wm1b + (size_t)(n0 + srow + 64) * 128 + kn + scol);
        }
        __syncthreads();
        short8 af[4], bf[4];
#pragma unroll
        for (int t = 0; t < 4; ++t) {
            af[t] = *(const short8*)&As[(wm + t * 16 + l15) * 32 + l4 * 8];
            bf[t] = *(const short8*)&Bs[(wn + t * 16 + l15) * 32 + l4 * 8];
        }
#pragma unroll
        for (int mt = 0; mt < 4; ++mt)
#pragma unroll
            for (int nt = 0; nt < 4; ++nt)
                acc[mt][nt] = __builtin_amdgcn_mfma_f32_16x16x32_bf16(af[mt], bf[nt], acc[mt][nt], 0, 0, 0);
    }

    int rl = lane >> 3;
    int cg = lane & 7;
#pragma unroll
    for (int mt = 0; mt < 4; ++mt) {
#pragma unroll
        for (int nt = 0; nt < 4; ++nt) {
            int col = n0 + wn + nt * 16 + l15;
            float bs = bm1[col];
#pragma unroll
            for (int r = 0; r < 4; ++r) {
                float v = fmaxf(acc[mt][nt][r] + bs, 0.0f);
                Cs[wave][(l4 * 4 + r) * 72 + nt * 16 + l15] = f2b(v);
            }
        }
#pragma unroll
        for (int p = 0; p < 2; ++p) {
            int lrow = p * 8 + rl;
            uint4 wv = *(const uint4*)&Cs[wave][lrow * 72 + cg * 8];
            int grow = m0 + wm + mt * 16 + lrow;
            *(uint4*)(hidb + (size_t)grow * 256 + n0 + wn + cg * 8) = wv;
        }
    }
}

// ---------------- final = bn3(out2), affine in-block, bf16 -> fp32 ----------------
__global__ __launch_bounds__(256) void final_bn(const u16* __restrict__ X,
                                                const float* __restrict__ sum3,
                                                const float* __restrict__ sq3,
                                                const float* __restrict__ g3,
                                                const float* __restrict__ bt3,
                                                float* __restrict__ outp) {
    __shared__ float A3[128], B3[128];
    int t = threadIdx.x;
    if (t < 128) {
        float s = 0.f, q = 0.f;
#pragma unroll
        for (int sl = 0; sl < SSLOT; ++sl) { s += sum3[sl * 128 + t]; q += sq3[sl * 128 + t]; }
        float m = s * (1.0f / NT);
        float v = q * (1.0f / NT) - m * m;
        float a = g3[t] * rsqrtf(v + EPS);
        A3[t] = a;
        B3[t] = bt3[t] - m * a;
    }
    __syncthreads();
    int i8 = blockIdx.x * 256 + t;
    size_t i = (size_t)i8 * 8;
    int c = (int)(i & (CCH - 1));
    uint4 u = *(const uint4*)(X + i);
    float x[8];
    x[0] = b2f(u.x & 0xffffu); x[1] = b2f(u.x >> 16);
    x[2] = b2f(u.y & 0xffffu); x[3] = b2f(u.y >> 16);
    x[4] = b2f(u.z & 0xffffu); x[5] = b2f(u.z >> 16);
    x[6] = b2f(u.w & 0xffffu); x[7] = b2f(u.w >> 16);
    float4 o0, o1;
    o0.x = A3[c + 0] * x[0] + B3[c + 0];
    o0.y = A3[c + 1] * x[1] + B3[c + 1];
    o0.z = A3[c + 2] * x[2] + B3[c + 2];
    o0.w = A3[c + 3] * x[3] + B3[c + 3];
    o1.x = A3[c + 4] * x[4] + B3[c + 4];
    o1.y = A3[c + 5] * x[5] + B3[c + 5];
    o1.z = A3[c + 6] * x[6] + B3[c + 6];
    o1.w = A3[c + 7] * x[7] + B3[c + 7];
    *(float4*)(outp + i) = o0;
    *(float4*)(outp + i + 4) = o1;
}

extern "C" void kernel_launch(void* const* d_in, const int* in_sizes, int n_in,
                              void* d_out, int out_size, void* d_ws, size_t ws_size,
                              hipStream_t stream) {
    const float* x    = (const float*)d_in[0];
    const int*   ei   = (const int*)d_in[1];
    const float* Wc   = (const float*)d_in[2];
    const float* bc   = (const float*)d_in[3];
    const float* Wqkv = (const float*)d_in[4];
    const float* bqkv = (const float*)d_in[5];
    const float* Wo   = (const float*)d_in[6];
    const float* bo   = (const float*)d_in[7];
    const float* gn1  = (const float*)d_in[8];
    const float* bn1b = (const float*)d_in[9];
    const float* gn2  = (const float*)d_in[10];
    const float* bn2b = (const float*)d_in[11];
    const float* gn3  = (const float*)d_in[12];
    const float* bn3b = (const float*)d_in[13];
    const float* Wm1  = (const float*)d_in[14];
    const float* bm1  = (const float*)d_in[15];
    const float* Wm2  = (const float*)d_in[16];
    const float* bm2  = (const float*)d_in[17];
    float* outp = (float*)d_out;

    char* w = (char*)d_ws;
    const size_t MB = 1024 * 1024;
    u16* xb    = (u16*)(w);                     //  8 MB
    u16* hlocb = (u16*)(w + 8 * MB);            //  8 MB
    u16* t2b   = (u16*)(w + 16 * MB);           //  8 MB  h_attn
    u16* out2b = (u16*)(w + 24 * MB);           //  8 MB
    u16* qkvb  = (u16*)(w + 32 * MB);           // 24 MB
    u16* hidb  = (u16*)(w + 56 * MB);           // 16 MB  [NT,256]
    u16* shb   = (u16*)(w + 72 * MB);           //  8 MB  aggb -> comb
    int* bucket = (int*)(w + 80 * MB);          // 12 MB
    int* cursor = (int*)(w + 92 * MB);          //  2 MB (padded: 1 counter / 64B line)
    float* stats = (float*)(w + 94 * MB);       //  stats (6x1024 floats) + bqs (384 floats)
    u16* Wcb   = (u16*)(w + 95 * MB);
    u16* Wqkvb = Wcb + 16384;
    u16* Wob   = Wqkvb + 49152;
    u16* Wm1b  = Wob + 16384;
    u16* Wm2b  = Wm1b + 32768;
    u16* ob    = (u16*)(w + 96 * MB);           //  8 MB  attention output (own buffer)
    float* sum1 = stats;                  float* sq1 = stats + 1024;
    float* sum2 = stats + 2048;           float* sq2 = stats + 3072;
    float* sum3 = stats + 4096;           float* sq3 = stats + 5120;
    float* bqs  = stats + 6144;           // prescaled qkv bias (384 floats)

    // cursor (2 MB) and stats+bqs (contiguous) in one memset
    hipMemsetAsync(cursor, 0, 2 * MB + 7 * 1024 * 4, stream);

    // conv (blocks 0..2119) + bias prescale (2120) + XCD-partitioned fill (2128..4175); LDS = 0
    prep_kernel<<<FILL0 + 2048, 256, 0, stream>>>(x, Wc, Wqkv, Wo, Wm1, Wm2,
                                                  xb, Wcb, Wqkvb, Wob, Wm1b, Wm2b,
                                                  bqkv, bqs, ei, cursor, bucket);

    {
        dim3 g(NT / 128, 3);
        gemm_qkv<<<g, 256, 0, stream>>>(xb, Wqkvb, bqs, qkvb);
    }

    // fused: attention (256 blocks, 8 waves) co-scheduled with pure gather (256 blocks, 8 waves)
    attn_gath<<<512, 512, 0, stream>>>(qkvb, ob, bucket, cursor, xb, shb /*aggb*/);

    // fused dual GEMM: Wc (y=0, A=aggb) + Wo (y=1, A=ob); both resid xb + stats
    {
        dim3 g(NT / 128, 2);
        gemm_wc_wo<<<g, 256, 0, stream>>>(shb, Wcb, bc, ob, Wob, bo, xb,
                                          hlocb, t2b, sum1, sq1, sum2, sq2);
    }

    {
        dim3 g(NT / 128, 2);
        gemm_m1c<<<g, 256, 0, stream>>>(hlocb, t2b, sum1, sq1, gn1, bn1b,
                                        sum2, sq2, gn2, bn2b, shb, Wm1b, bm1, hidb);
    }

    gemm_mlp2<<<NT / 128, 256, 0, stream>>>(hidb, Wm2b, bm2, shb, out2b, sum3, sq3);

    final_bn<<<NT * CCH / 8 / 256, 256, 0, stream>>>(out2b, sum3, sq3, gn3, bn3b, outp);
}

// Round 13
// 208.116 us; speedup vs baseline: 1.0796x; 1.0118x over previous
//
#include <hip/hip_runtime.h>
#include <cstddef>

#define NT    32768
#define CCH   128
#define BB    64
#define NNODE 512
#define NHEAD 4
#define DHEAD 32
#define EE    524288
#define EPS   1e-5f
#define MAXDEG 96
#define CURPAD 16      // one cursor counter per 64B cache line
#define SSLOT  8       // stats atomic spreading slots
#define EGRP  2048     // edges per partition group (E / 256 groups)
#define FILL0 2128     // first fill block (8-aligned so (bid-FILL0)&7 == bid&7)

typedef unsigned short u16;
typedef unsigned int   u32;
typedef __attribute__((ext_vector_type(8))) short short8;
typedef __attribute__((ext_vector_type(4))) short short4v;
typedef __attribute__((ext_vector_type(4))) float f32x4;

__device__ __forceinline__ float b2f(u32 w) { return __uint_as_float(w << 16); }
__device__ __forceinline__ u16 f2b(float f) {
    u32 u = __float_as_uint(f);
    u += 0x7FFF + ((u >> 16) & 1);   // RNE
    return (u16)(u >> 16);
}
// packed f32x2 -> bf16x2 (RNE), single instruction; no builtin on gfx950 (guide T12)
__device__ __forceinline__ u32 cvtpk(float lo, float hi) {
    u32 r;
    asm("v_cvt_pk_bf16_f32 %0, %1, %2" : "=v"(r) : "v"(lo), "v"(hi));
    return r;
}
#if __has_builtin(__builtin_amdgcn_exp2f)
#define EXP2(x) __builtin_amdgcn_exp2f(x)
#else
#define EXP2(x) exp2f(x)
#endif
// softmax scale (1/sqrt(32)) * log2(e), folded into Wq/bq at conversion time
#define SCLOG2E (0.1767766952966369f * 1.4426950408889634f)

// ---------------- prep: bf16 conversion (Wq/bq prescaled) + XCD-partitioned bucket fill ------------
// NO __shared__: fill blocks need max occupancy (8 blocks/CU) for atomic/scatter TLP (round-10 lesson).
__global__ __launch_bounds__(256) void prep_kernel(const float* __restrict__ x,
                                                   const float* __restrict__ Wc,
                                                   const float* __restrict__ Wqkv,
                                                   const float* __restrict__ Wo,
                                                   const float* __restrict__ Wm1,
                                                   const float* __restrict__ Wm2,
                                                   u16* __restrict__ xb,
                                                   u16* __restrict__ Wcb,
                                                   u16* __restrict__ Wqkvb,
                                                   u16* __restrict__ Wob,
                                                   u16* __restrict__ Wm1b,
                                                   u16* __restrict__ Wm2b,
                                                   const float* __restrict__ bqkv,
                                                   float* __restrict__ bqs,
                                                   const int* __restrict__ ei,
                                                   int* __restrict__ cursor,
                                                   int* __restrict__ bucket) {
    int bid = blockIdx.x;
    if (bid >= FILL0) {
        int b2 = bid - FILL0;
        int k = b2 & 7;
        int g = b2 >> 3;
        int base_e = g * EGRP;
        for (int j = threadIdx.x; j < EGRP; j += 256) {
            int dst = ei[EE + base_e + j];
            if ((dst & 7) == k) {
                int src = ei[base_e + j];
                int pos = atomicAdd(cursor + dst * CURPAD, 1);
                if (pos < MAXDEG) bucket[dst * MAXDEG + pos] = src;
            }
        }
        return;
    }
    if (bid == 2120) {
        int t = threadIdx.x;
        if (t < 384) {
            float v = bqkv[t];
            if (t < 128) v *= SCLOG2E;
            bqs[t] = v;
        }
        return;
    }
    if (bid > 2120) return;   // 2121..2127 idle (alignment padding)
    int r = bid * 256 + threadIdx.x;
    const float* src; u16* dst; float qs = 1.0f;
    if (r < 524288) { src = x; dst = xb; }
    else if ((r -= 524288) < 2048) { src = Wc; dst = Wcb; }
    else if ((r -= 2048) < 6144) { src = Wqkv; dst = Wqkvb; if (r < 2048) qs = SCLOG2E; }
    else if ((r -= 6144) < 2048) { src = Wo; dst = Wob; }
    else if ((r -= 2048) < 4096) { src = Wm1; dst = Wm1b; }
    else { r -= 4096; src = Wm2; dst = Wm2b; }
    size_t base = (size_t)r * 8;
    float4 a = *(const float4*)(src + base);
    float4 b = *(const float4*)(src + base + 4);
    uint4 u;
    u.x = cvtpk(a.x * qs, a.y * qs);
    u.y = cvtpk(a.z * qs, a.w * qs);
    u.z = cvtpk(b.x * qs, b.y * qs);
    u.w = cvtpk(b.z * qs, b.w * qs);
    *(uint4*)(dst + base) = u;
}

// ---------------- shared GEMM smem + body: 128x128 tile, dbuf + wide stores (27.6 KB) ----------------
struct GemmSmem {
    u16 As[128 * 32];
    u16 Bs[128 * 32];
    u16 Cs[4][16 * 72];
    float csum[128];
    float csq[128];
};

// outb pre-offset to column 0 of this GEMM's output slice; ostride = its row stride.
// bias/residb indexed by LOCAL column (0..127); residb row stride = 128.
template <bool RELU, int RESID, bool STATS>
__device__ __forceinline__ void gemm_body(u16* __restrict__ As, u16* __restrict__ Bs,
                                          u16* __restrict__ Cs0, float* __restrict__ csum,
                                          float* __restrict__ csq,
                                          const u16* __restrict__ A,
                                          const u16* __restrict__ W,
                                          const float* __restrict__ bias,
                                          const u16* __restrict__ residb,
                                          u16* __restrict__ outb, int ostride,
                                          float* __restrict__ sum, float* __restrict__ sumsq,
                                          int slotbase, int m0, int K) {
    int tid = threadIdx.x;
    int lane = tid & 63, wave = tid >> 6;
    int wm = (wave & 1) * 64, wn = (wave >> 1) * 64;
    int l15 = lane & 15, l4 = lane >> 4;
    u16* Csw = Cs0 + wave * (16 * 72);

    if (STATS) {
        if (tid < 128) { csum[tid] = 0.f; csq[tid] = 0.f; }
    }

    f32x4 zero = {0.f, 0.f, 0.f, 0.f};
    f32x4 acc[4][4];
#pragma unroll
    for (int i = 0; i < 4; ++i)
#pragma unroll
        for (int j = 0; j < 4; ++j) acc[i][j] = zero;

    int srow = tid >> 2;
    int scol = (tid & 3) * 8;

    int kIter = K >> 5;
    uint4 a0 = *(const uint4*)(A + (size_t)(m0 + srow) * K + scol);
    uint4 a1 = *(const uint4*)(A + (size_t)(m0 + srow + 64) * K + scol);
    uint4 b0 = *(const uint4*)(W + (size_t)srow * K + scol);
    uint4 b1 = *(const uint4*)(W + (size_t)(srow + 64) * K + scol);
    for (int ki = 0; ki < kIter; ++ki) {
        if (ki) __syncthreads();
        *(uint4*)&As[srow * 32 + scol] = a0;
        *(uint4*)&As[(srow + 64) * 32 + scol] = a1;
        *(uint4*)&Bs[srow * 32 + scol] = b0;
        *(uint4*)&Bs[(srow + 64) * 32 + scol] = b1;
        if (ki + 1 < kIter) {
            int k0 = (ki + 1) * 32;
            a0 = *(const uint4*)(A + (size_t)(m0 + srow) * K + k0 + scol);
            a1 = *(const uint4*)(A + (size_t)(m0 + srow + 64) * K + k0 + scol);
            b0 = *(const uint4*)(W + (size_t)srow * K + k0 + scol);
            b1 = *(const uint4*)(W + (size_t)(srow + 64) * K + k0 + scol);
        }
        __syncthreads();
        short8 af[4], bf[4];
#pragma unroll
        for (int t = 0; t < 4; ++t) {
            af[t] = *(const short8*)&As[(wm + t * 16 + l15) * 32 + l4 * 8];
            bf[t] = *(const short8*)&Bs[(wn + t * 16 + l15) * 32 + l4 * 8];
        }
#pragma unroll
        for (int mt = 0; mt < 4; ++mt)
#pragma unroll
            for (int nt = 0; nt < 4; ++nt)
                acc[mt][nt] = __builtin_amdgcn_mfma_f32_16x16x32_bf16(af[mt], bf[nt], acc[mt][nt], 0, 0, 0);
    }

    float ps[4] = {0.f, 0.f, 0.f, 0.f};
    float pq[4] = {0.f, 0.f, 0.f, 0.f};
    int rl = lane >> 3;          // 0..7
    int cg = lane & 7;           // 0..7
#pragma unroll
    for (int mt = 0; mt < 4; ++mt) {
#pragma unroll
        for (int nt = 0; nt < 4; ++nt) {
            int lcol = wn + nt * 16 + l15;
            float bs = bias[lcol];
#pragma unroll
            for (int r = 0; r < 4; ++r) {
                int row = m0 + wm + mt * 16 + l4 * 4 + r;
                float v = acc[mt][nt][r] + bs;
                if (RESID == 2) v += b2f(residb[(size_t)row * 128 + lcol]);
                if (RELU) v = fmaxf(v, 0.0f);
                Csw[(l4 * 4 + r) * 72 + nt * 16 + l15] = f2b(v);
                if (STATS) { ps[nt] += v; pq[nt] += v * v; }
            }
        }
        // wide readback + coalesced store (wave-private, DS in-order: no barrier)
#pragma unroll
        for (int p = 0; p < 2; ++p) {
            int lrow = p * 8 + rl;
            uint4 wv = *(const uint4*)&Csw[lrow * 72 + cg * 8];
            int grow = m0 + wm + mt * 16 + lrow;
            *(uint4*)(outb + (size_t)grow * ostride + wn + cg * 8) = wv;
        }
    }
    if (STATS) {
#pragma unroll
        for (int nt = 0; nt < 4; ++nt) {
            atomicAdd(&csum[wn + nt * 16 + l15], ps[nt]);
            atomicAdd(&csq[wn + nt * 16 + l15], pq[nt]);
        }
        __syncthreads();
        if (tid < 128) {
            atomicAdd(sum + slotbase + tid, csum[tid]);
            atomicAdd(sumsq + slotbase + tid, csq[tid]);
        }
    }
}

// ---------------- QKV GEMM (standalone; runs between prep and the attn+gather fusion) ----------------
__global__ __launch_bounds__(256) void gemm_qkv(const u16* __restrict__ xb,
                                                const u16* __restrict__ Wqkvb,
                                                const float* __restrict__ bqs,
                                                u16* __restrict__ qkvb) {
    __shared__ GemmSmem sm;
    int y = blockIdx.y;
    gemm_body<false, 0, false>(sm.As, sm.Bs, &sm.Cs[0][0], sm.csum, sm.csq,
                               xb, Wqkvb + (size_t)y * 16384, bqs + y * 128, nullptr,
                               qkvb + y * 128, 384, nullptr, nullptr, 0, blockIdx.x * 128, 128);
}

// ---------------- fused: attention (bid<256) + gather (bid>=256, 512 blocks x 64 nodes) -----------
// 512-thread blocks, 74KB LDS union -> 2 blocks/CU. Co-residency: 1 attn + 1 gather per CU.
// Gather split to 512x64-node blocks so the post-attn TAIL runs 2 gather blocks/CU (16 waves)
// instead of round-12's 1 block (8 waves) with an empty LDS slot.
struct AGSmem {
    union {
        struct { u16 Ks[512 * 40]; u16 Vt[32 * 520]; } a;   // 72.5 KB attention
        int srcs[32][MAXDEG];                                // 12 KB gather
    };
};

__global__ __launch_bounds__(512) void attn_gath(const u16* __restrict__ qkv,
                                                 u16* __restrict__ o,
                                                 const int* __restrict__ bucket,
                                                 const int* __restrict__ cursor,
                                                 const u16* __restrict__ xb,
                                                 u16* __restrict__ aggb) {
    __shared__ __align__(16) AGSmem sm;
    int bid = blockIdx.x;
    int tid = threadIdx.x;

    if (bid < 256) {
        // ---- attention branch: 8 waves, 4 q-tiles each; exp2-folded softmax + cvt_pk pack ----
        u16* Ks = sm.a.Ks;
        u16* Vt = sm.a.Vt;
        int b = bid >> 2, h = bid & 3;
        int lane = tid & 63, wave = tid >> 6;
        int quad = lane >> 4, l15 = lane & 15;

        const u16* kvbase = qkv + (size_t)b * 512 * 384 + 128 + h * 32;
        for (int idx = tid; idx < 2048; idx += 512) {
            int row = idx >> 2, c = idx & 3;
            *(uint4*)&Ks[row * 40 + c * 8] = *(const uint4*)(kvbase + (size_t)row * 384 + c * 8);
        }
        for (int idx = tid; idx < 2048; idx += 512) {
            int row = idx >> 2, c = idx & 3;
            uint4 u = *(const uint4*)(kvbase + 128 + (size_t)row * 384 + c * 8);
            u16 e[8];
            *(uint4*)e = u;
#pragma unroll
            for (int i = 0; i < 8; ++i) Vt[(c * 8 + i) * 520 + row] = e[i];
        }
        __syncthreads();

        f32x4 zero = {0.f, 0.f, 0.f, 0.f};
        for (int qt = 0; qt < 4; ++qt) {
            int qbase = wave * 64 + qt * 16;
            short8 qf = *(const short8*)(qkv + (size_t)(b * 512 + qbase + l15) * 384 + h * 32 + quad * 8);
            float lq = 0.f;
            f32x4 oa[2] = {zero, zero};

            for (int kv0 = 0; kv0 < 512; kv0 += 64) {
                f32x4 s[4];
#pragma unroll
                for (int t = 0; t < 4; ++t) {
                    short8 kb = *(const short8*)&Ks[(kv0 + t * 16 + l15) * 40 + quad * 8];
                    s[t] = __builtin_amdgcn_mfma_f32_16x16x32_bf16(kb, qf, zero, 0, 0, 0);
                }
                u32 ppw[2][4];
#pragma unroll
                for (int t = 0; t < 4; ++t) {
                    float p0 = EXP2(s[t][0]);
                    float p1 = EXP2(s[t][1]);
                    float p2 = EXP2(s[t][2]);
                    float p3 = EXP2(s[t][3]);
                    lq += (p0 + p1) + (p2 + p3);
                    ppw[t >> 1][(t & 1) * 2 + 0] = cvtpk(p0, p1);
                    ppw[t >> 1][(t & 1) * 2 + 1] = cvtpk(p2, p3);
                }
                short8 pps[2];
                pps[0] = *(const short8*)&ppw[0][0];
                pps[1] = *(const short8*)&ppw[1][0];
#pragma unroll
                for (int tp = 0; tp < 2; ++tp) {
                    int tb = kv0 + tp * 32;
#pragma unroll
                    for (int n = 0; n < 2; ++n) {
                        const u16* vrow = &Vt[(n * 16 + l15) * 520 + tb + quad * 4];
                        short4v va = *(const short4v*)vrow;          // kv tile 2tp
                        short4v vb2 = *(const short4v*)(vrow + 16);  // kv tile 2tp+1
                        short8 vv = {va.x, va.y, va.z, va.w, vb2.x, vb2.y, vb2.z, vb2.w};
                        oa[n] = __builtin_amdgcn_mfma_f32_16x16x32_bf16(pps[tp], vv, oa[n], 0, 0, 0);
                    }
                }
            }
            lq += __shfl_xor(lq, 16);
            lq += __shfl_xor(lq, 32);
            u16* op = o + (size_t)(b * 512 + qbase) * 128 + h * 32;
#pragma unroll
            for (int r = 0; r < 4; ++r) {
                float Lr = __shfl(lq, quad * 4 + r);
                float inv = 1.0f / Lr;
#pragma unroll
                for (int n = 0; n < 2; ++n)
                    op[(quad * 4 + r) * 128 + n * 16 + l15] = f2b(oa[n][r] * inv);
            }
        }
        return;
    }

    // ---- pure gather branch: 64 nodes/block, 32 node-groups x 16 ch-lanes, 2 passes, 8-deep ----
    {
        int m0 = (bid - 256) * 64;
        int ln = tid >> 4;     // node-in-pass 0..31
        int c8 = tid & 15;     // channel block of 8
        const u16* xp = xb + c8 * 8;
        for (int pass = 0; pass < 2; ++pass) {
            int n = pass * 32 + ln;          // local row 0..63
            int gn = m0 + n;
            int d = min(cursor[gn * CURPAD], MAXDEG);
            for (int j = c8; j < d; j += 16) sm.srcs[ln][j] = bucket[gn * MAXDEG + j];
            __syncthreads();
            float s[8] = {0.f, 0.f, 0.f, 0.f, 0.f, 0.f, 0.f, 0.f};
            for (int base = 0; base < d; base += 8) {
                uint4 w[8];
#pragma unroll
                for (int u = 0; u < 8; ++u) {
                    int jj = base + u;
                    int idx = sm.srcs[ln][jj < d ? jj : 0];
                    w[u] = *(const uint4*)(xp + (size_t)idx * CCH);
                }
#pragma unroll
                for (int u = 0; u < 8; ++u) {
                    if (base + u >= d) { w[u].x = 0; w[u].y = 0; w[u].z = 0; w[u].w = 0; }
                    s[0] += b2f(w[u].x & 0xffffu);
                    s[1] += b2f(w[u].x >> 16);
                    s[2] += b2f(w[u].y & 0xffffu);
                    s[3] += b2f(w[u].y >> 16);
                    s[4] += b2f(w[u].z & 0xffffu);
                    s[5] += b2f(w[u].z >> 16);
                    s[6] += b2f(w[u].w & 0xffffu);
                    s[7] += b2f(w[u].w >> 16);
                }
            }
            float inv = 1.0f / fmaxf((float)d, 1.0f);
            uint4 out;
            out.x = cvtpk(s[0] * inv, s[1] * inv);
            out.y = cvtpk(s[2] * inv, s[3] * inv);
            out.z = cvtpk(s[4] * inv, s[5] * inv);
            out.w = cvtpk(s[6] * inv, s[7] * inv);
            *(uint4*)(aggb + (size_t)gn * CCH + c8 * 8) = out;
            __syncthreads();   // srcs reused next pass
        }
    }
}

// ---------------- fused dual GEMM: y=0 Wc (h_local <- aggb), y=1 Wo (h_attn <- ob) ----------------
__global__ __launch_bounds__(256) void gemm_wc_wo(const u16* __restrict__ aggb,
                                                  const u16* __restrict__ Wcb,
                                                  const float* __restrict__ bc,
                                                  const u16* __restrict__ ob,
                                                  const u16* __restrict__ Wob,
                                                  const float* __restrict__ bo,
                                                  const u16* __restrict__ xb,
                                                  u16* __restrict__ hlocb,
                                                  u16* __restrict__ t2b,
                                                  float* __restrict__ sum1, float* __restrict__ sq1,
                                                  float* __restrict__ sum2, float* __restrict__ sq2) {
    __shared__ GemmSmem sm;
    bool wo = (blockIdx.y != 0);
    int m0 = blockIdx.x * 128;
    int slotbase = (blockIdx.x & (SSLOT - 1)) << 7;
    gemm_body<false, 2, true>(sm.As, sm.Bs, &sm.Cs[0][0], sm.csum, sm.csq,
                              wo ? ob : aggb,
                              wo ? Wob : Wcb,
                              wo ? bo : bc,
                              xb,
                              wo ? t2b : hlocb, 128,
                              wo ? sum2 : sum1,
                              wo ? sq2 : sq1,
                              slotbase, m0, 128);
}

// ---------------- MLP2 GEMM wrapper ----------------
__global__ __launch_bounds__(256) void gemm_mlp2(const u16* __restrict__ hidb,
                                                 const u16* __restrict__ Wm2b,
                                                 const float* __restrict__ bm2,
                                                 const u16* __restrict__ shb,
                                                 u16* __restrict__ out2b,
                                                 float* __restrict__ sum3, float* __restrict__ sq3) {
    __shared__ GemmSmem sm;
    gemm_body<false, 2, true>(sm.As, sm.Bs, &sm.Cs[0][0], sm.csum, sm.csq,
                              hidb, Wm2b, bm2, shb, out2b, 128, sum3, sq3,
                              (blockIdx.x & (SSLOT - 1)) << 7, blockIdx.x * 128, 256);
}

// ---------------- MLP1 GEMM with comb fused into A-staging; dbuf + wide stores ----------------
__global__ __launch_bounds__(256) void gemm_m1c(const u16* __restrict__ hlocb,
                                                const u16* __restrict__ t2b,
                                                const float* __restrict__ sum1,
                                                const float* __restrict__ sq1,
                                                const float* __restrict__ g1,
                                                const float* __restrict__ bt1,
                                                const float* __restrict__ sum2,
                                                const float* __restrict__ sq2,
                                                const float* __restrict__ g2,
                                                const float* __restrict__ bt2,
                                                u16* __restrict__ shb,
                                                const u16* __restrict__ Wm1b,
                                                const float* __restrict__ bm1,
                                                u16* __restrict__ hidb) {
    __shared__ u16 As[128 * 32];
    __shared__ u16 Bs[128 * 32];
    __shared__ u16 Cs[4][16 * 72];
    __shared__ float AF1[128], BF1[128], AF2[128], BF2[128];
    int tid = threadIdx.x;
    {
        int c = tid & 127;
        const float* sm = (tid < 128) ? sum1 : sum2;
        const float* sq = (tid < 128) ? sq1 : sq2;
        const float* g  = (tid < 128) ? g1 : g2;
        const float* bt = (tid < 128) ? bt1 : bt2;
        float s = 0.f, q = 0.f;
#pragma unroll
        for (int sl = 0; sl < SSLOT; ++sl) { s += sm[sl * 128 + c]; q += sq[sl * 128 + c]; }
        float m = s * (1.0f / NT);
        float v = q * (1.0f / NT) - m * m;
        float a = g[c] * rsqrtf(v + EPS);
        if (tid < 128) { AF1[c] = a; BF1[c] = bt[c] - m * a; }
        else           { AF2[c] = a; BF2[c] = bt[c] - m * a; }
    }
    int m0 = blockIdx.x * 128, n0 = blockIdx.y * 128;
    int lane = tid & 63, wave = tid >> 6;
    int wm = (wave & 1) * 64, wn = (wave >> 1) * 64;
    int l15 = lane & 15, l4 = lane >> 4;

    f32x4 zero = {0.f, 0.f, 0.f, 0.f};
    f32x4 acc[4][4];
#pragma unroll
    for (int i = 0; i < 4; ++i)
#pragma unroll
        for (int j = 0; j < 4; ++j) acc[i][j] = zero;

    int srow = tid >> 2;
    int scol = (tid & 3) * 8;
    bool wr = (blockIdx.y == 0);

    uint4 h0 = *(const uint4*)(hlocb + (size_t)(m0 + srow) * 128 + scol);
    uint4 h1 = *(const uint4*)(hlocb + (size_t)(m0 + srow + 64) * 128 + scol);
    uint4 t0 = *(const uint4*)(t2b + (size_t)(m0 + srow) * 128 + scol);
    uint4 t1 = *(const uint4*)(t2b + (size_t)(m0 + srow + 64) * 128 + scol);
    uint4 b0 = *(const uint4*)(Wm1b + (size_t)(n0 + srow) * 128 + scol);
    uint4 b1 = *(const uint4*)(Wm1b + (size_t)(n0 + srow + 64) * 128 + scol);
    // barrier for AF/BF shared arrays before first use
    __syncthreads();
    for (int ki = 0; ki < 4; ++ki) {
        int k0 = ki * 32;
        if (ki) __syncthreads();
        uint4 c0, c1;
        {
            const u32 hw[4] = {h0.x, h0.y, h0.z, h0.w};
            const u32 tw[4] = {t0.x, t0.y, t0.z, t0.w};
            u32 ow[4];
#pragma unroll
            for (int p = 0; p < 4; ++p) {
                int cc = k0 + scol + p * 2;
                float v0 = AF1[cc] * b2f(hw[p] & 0xffffu) + BF1[cc] + AF2[cc] * b2f(tw[p] & 0xffffu) + BF2[cc];
                float v1 = AF1[cc + 1] * b2f(hw[p] >> 16) + BF1[cc + 1] + AF2[cc + 1] * b2f(tw[p] >> 16) + BF2[cc + 1];
                ow[p] = cvtpk(v0, v1);
            }
            c0.x = ow[0]; c0.y = ow[1]; c0.z = ow[2]; c0.w = ow[3];
        }
        {
            const u32 hw[4] = {h1.x, h1.y, h1.z, h1.w};
            const u32 tw[4] = {t1.x, t1.y, t1.z, t1.w};
            u32 ow[4];
#pragma unroll
            for (int p = 0; p < 4; ++p) {
                int cc = k0 + scol + p * 2;
                float v0 = AF1[cc] * b2f(hw[p] & 0xffffu) + BF1[cc] + AF2[cc] * b2f(tw[p] & 0xffffu) + BF2[cc];
                float v1 = AF1[cc + 1] * b2f(hw[p] >> 16) + BF1[cc + 1] + AF2[cc + 1] * b2f(tw[p] >> 16) + BF2[cc + 1];
                ow[p] = cvtpk(v0, v1);
            }
            c1.x = ow[0]; c1.y = ow[1]; c1.z = ow[2]; c1.w = ow[3];
        }
        *(uint4*)&As[srow * 32 + scol] = c0;
        *(uint4*)&As[(srow + 64) * 32 + scol] = c1;
        *(uint4*)&Bs[srow * 32 + scol] = b0;
        *(uint4*)&Bs[(srow + 64) * 32 + scol] = b1;
        if (wr) {
            *(uint4*)(shb + (size_t)(m0 + srow) * 128 + k0 + scol) = c0;
            *(uint4*)(shb + (size_t)(m0 + srow + 64) * 128 + k0 + scol) = c1;
        }
        if (ki < 3) {
            int kn = k0 + 32;
            h0 = *(const uint4*)(hlocb + (size_t)(m0 + srow) * 128 + kn + scol);
            h1 = *(const uint4*)(hlocb + (size_t)(m0 + srow + 64) * 128 + kn + scol);
            t0 = *(const uint4*)(t2b + (size_t)(m0 + srow) * 128 + kn + scol);
            t1 = *(const uint4*)(t2b + (size_t)(m0 + srow + 64) * 128 + kn + scol);
            b0 = *(const uint4*)(Wm1b + (size_t)(n0 + srow) * 128 + kn + scol);
            b1 = *(const uint4*)(Wm1b + (size_t)(n0 + srow + 64) * 128 + kn + scol);
        }
        __syncthreads();
        short8 af[4], bf[4];
#pragma unroll
        for (int t = 0; t < 4; ++t) {
            af[t] = *(const short8*)&As[(wm + t * 16 + l15) * 32 + l4 * 8];
            bf[t] = *(const short8*)&Bs[(wn + t * 16 + l15) * 32 + l4 * 8];
        }
#pragma unroll
        for (int mt = 0; mt < 4; ++mt)
#pragma unroll
            for (int nt = 0; nt < 4; ++nt)
                acc[mt][nt] = __builtin_amdgcn_mfma_f32_16x16x32_bf16(af[mt], bf[nt], acc[mt][nt], 0, 0, 0);
    }

    int rl = lane >> 3;
    int cg = lane & 7;
#pragma unroll
    for (int mt = 0; mt < 4; ++mt) {
#pragma unroll
        for (int nt = 0; nt < 4; ++nt) {
            int col = n0 + wn + nt * 16 + l15;
            float bs = bm1[col];
#pragma unroll
            for (int r = 0; r < 4; ++r) {
                float v = fmaxf(acc[mt][nt][r] + bs, 0.0f);
                Cs[wave][(l4 * 4 + r) * 72 + nt * 16 + l15] = f2b(v);
            }
        }
#pragma unroll
        for (int p = 0; p < 2; ++p) {
            int lrow = p * 8 + rl;
            uint4 wv = *(const uint4*)&Cs[wave][lrow * 72 + cg * 8];
            int grow = m0 + wm + mt * 16 + lrow;
            *(uint4*)(hidb + (size_t)grow * 256 + n0 + wn + cg * 8) = wv;
        }
    }
}

// ---------------- final = bn3(out2), affine in-block, bf16 -> fp32 ----------------
__global__ __launch_bounds__(256) void final_bn(const u16* __restrict__ X,
                                                const float* __restrict__ sum3,
                                                const float* __restrict__ sq3,
                                                const float* __restrict__ g3,
                                                const float* __restrict__ bt3,
                                                float* __restrict__ outp) {
    __shared__ float A3[128], B3[128];
    int t = threadIdx.x;
    if (t < 128) {
        float s = 0.f, q = 0.f;
#pragma unroll
        for (int sl = 0; sl < SSLOT; ++sl) { s += sum3[sl * 128 + t]; q += sq3[sl * 128 + t]; }
        float m = s * (1.0f / NT);
        float v = q * (1.0f / NT) - m * m;
        float a = g3[t] * rsqrtf(v + EPS);
        A3[t] = a;
        B3[t] = bt3[t] - m * a;
    }
    __syncthreads();
    int i8 = blockIdx.x * 256 + t;
    size_t i = (size_t)i8 * 8;
    int c = (int)(i & (CCH - 1));
    uint4 u = *(const uint4*)(X + i);
    float x[8];
    x[0] = b2f(u.x & 0xffffu); x[1] = b2f(u.x >> 16);
    x[2] = b2f(u.y & 0xffffu); x[3] = b2f(u.y >> 16);
    x[4] = b2f(u.z & 0xffffu); x[5] = b2f(u.z >> 16);
    x[6] = b2f(u.w & 0xffffu); x[7] = b2f(u.w >> 16);
    float4 o0, o1;
    o0.x = A3[c + 0] * x[0] + B3[c + 0];
    o0.y = A3[c + 1] * x[1] + B3[c + 1];
    o0.z = A3[c + 2] * x[2] + B3[c + 2];
    o0.w = A3[c + 3] * x[3] + B3[c + 3];
    o1.x = A3[c + 4] * x[4] + B3[c + 4];
    o1.y = A3[c + 5] * x[5] + B3[c + 5];
    o1.z = A3[c + 6] * x[6] + B3[c + 6];
    o1.w = A3[c + 7] * x[7] + B3[c + 7];
    *(float4*)(outp + i) = o0;
    *(float4*)(outp + i + 4) = o1;
}

extern "C" void kernel_launch(void* const* d_in, const int* in_sizes, int n_in,
                              void* d_out, int out_size, void* d_ws, size_t ws_size,
                              hipStream_t stream) {
    const float* x    = (const float*)d_in[0];
    const int*   ei   = (const int*)d_in[1];
    const float* Wc   = (const float*)d_in[2];
    const float* bc   = (const float*)d_in[3];
    const float* Wqkv = (const float*)d_in[4];
    const float* bqkv = (const float*)d_in[5];
    const float* Wo   = (const float*)d_in[6];
    const float* bo   = (const float*)d_in[7];
    const float* gn1  = (const float*)d_in[8];
    const float* bn1b = (const float*)d_in[9];
    const float* gn2  = (const float*)d_in[10];
    const float* bn2b = (const float*)d_in[11];
    const float* gn3  = (const float*)d_in[12];
    const float* bn3b = (const float*)d_in[13];
    const float* Wm1  = (const float*)d_in[14];
    const float* bm1  = (const float*)d_in[15];
    const float* Wm2  = (const float*)d_in[16];
    const float* bm2  = (const float*)d_in[17];
    float* outp = (float*)d_out;

    char* w = (char*)d_ws;
    const size_t MB = 1024 * 1024;
    u16* xb    = (u16*)(w);                     //  8 MB
    u16* hlocb = (u16*)(w + 8 * MB);            //  8 MB
    u16* t2b   = (u16*)(w + 16 * MB);           //  8 MB  h_attn
    u16* out2b = (u16*)(w + 24 * MB);           //  8 MB
    u16* qkvb  = (u16*)(w + 32 * MB);           // 24 MB
    u16* hidb  = (u16*)(w + 56 * MB);           // 16 MB  [NT,256]
    u16* shb   = (u16*)(w + 72 * MB);           //  8 MB  aggb -> comb
    int* bucket = (int*)(w + 80 * MB);          // 12 MB
    int* cursor = (int*)(w + 92 * MB);          //  2 MB (padded: 1 counter / 64B line)
    float* stats = (float*)(w + 94 * MB);       //  stats (6x1024 floats) + bqs (384 floats)
    u16* Wcb   = (u16*)(w + 95 * MB);
    u16* Wqkvb = Wcb + 16384;
    u16* Wob   = Wqkvb + 49152;
    u16* Wm1b  = Wob + 16384;
    u16* Wm2b  = Wm1b + 32768;
    u16* ob    = (u16*)(w + 96 * MB);           //  8 MB  attention output (own buffer)
    float* sum1 = stats;                  float* sq1 = stats + 1024;
    float* sum2 = stats + 2048;           float* sq2 = stats + 3072;
    float* sum3 = stats + 4096;           float* sq3 = stats + 5120;
    float* bqs  = stats + 6144;           // prescaled qkv bias (384 floats)

    // cursor (2 MB) and stats+bqs (contiguous) in one memset
    hipMemsetAsync(cursor, 0, 2 * MB + 7 * 1024 * 4, stream);

    // conv (blocks 0..2119) + bias prescale (2120) + XCD-partitioned fill (2128..4175); LDS = 0
    prep_kernel<<<FILL0 + 2048, 256, 0, stream>>>(x, Wc, Wqkv, Wo, Wm1, Wm2,
                                                  xb, Wcb, Wqkvb, Wob, Wm1b, Wm2b,
                                                  bqkv, bqs, ei, cursor, bucket);

    {
        dim3 g(NT / 128, 3);
        gemm_qkv<<<g, 256, 0, stream>>>(xb, Wqkvb, bqs, qkvb);
    }

    // fused: attention (256 blocks) + gather (512 blocks x 64 nodes) — tail runs 2 gather blocks/CU
    attn_gath<<<768, 512, 0, stream>>>(qkvb, ob, bucket, cursor, xb, shb /*aggb*/);

    // fused dual GEMM: Wc (y=0, A=aggb) + Wo (y=1, A=ob); both resid xb + stats
    {
        dim3 g(NT / 128, 2);
        gemm_wc_wo<<<g, 256, 0, stream>>>(shb, Wcb, bc, ob, Wob, bo, xb,
                                          hlocb, t2b, sum1, sq1, sum2, sq2);
    }

    {
        dim3 g(NT / 128, 2);
        gemm_m1c<<<g, 256, 0, stream>>>(hlocb, t2b, sum1, sq1, gn1, bn1b,
                                        sum2, sq2, gn2, bn2b, shb, Wm1b, bm1, hidb);
    }

    gemm_mlp2<<<NT / 128, 256, 0, stream>>>(hidb, Wm2b, bm2, shb, out2b, sum3, sq3);

    final_bn<<<NT * CCH / 8 / 256, 256, 0, stream>>>(out2b, sum3, sq3, gn3, bn3b, outp);
}